// Round 5
// baseline (472.147 us; speedup 1.0000x reference)
//
#include <hip/hip_runtime.h>
#include <hip/hip_bf16.h>
#include <stdint.h>

// Problem constants
constexpr int BATCH = 64;
constexpr int NTOK  = 197;
constexpr int CDIM  = 768;
constexpr int NH    = 12;
constexpr int HD    = 64;
constexpr int MROWS = BATCH * NTOK;        // 12608
constexpr int MPAD  = 12800;               // 100 * 128 (GEMM row tiles)
constexpr int NROWT = MPAD / 128;          // 100
constexpr int LEFT  = 137;                 // int(0.7 * 196)
constexpr int KPAD  = 224;                 // keys padded (7 * 32)
constexpr int BH    = BATCH * NH;          // 768
constexpr int SPAD  = 208;                 // score row stride

// Output layout (flat float32, concatenated in return order)
constexpr size_t OUT_OFF_OUT   = 0;                                   // [64,197,768]
constexpr size_t OUT_OFF_INDEX = (size_t)BATCH * NTOK * CDIM;         // [64,137,768]
constexpr size_t OUT_OFF_IDX   = OUT_OFF_INDEX + (size_t)BATCH * LEFT * CDIM; // [64,137]
constexpr size_t OUT_OFF_CLS   = OUT_OFF_IDX + (size_t)BATCH * LEFT;  // [64,196]

// Workspace layout (float units; bf16 regions counted as elems/2)
constexpr size_t WS_CLSPH = 0;                                        // (unused, kept for layout)
constexpr size_t WS_CLSF  = WS_CLSPH + (size_t)BH * (NTOK - 1);
constexpr size_t WS_IDXI  = WS_CLSF  + (size_t)BATCH * (NTOK - 1);
constexpr size_t WS_Q0    = WS_IDXI  + (size_t)BATCH * LEFT;          // [64,768]
constexpr size_t WS_XB    = WS_Q0  + (size_t)BATCH * CDIM;            // [MPAD,768] bf16
constexpr size_t WS_WB    = WS_XB  + (size_t)MPAD * CDIM / 2;         // [2304,768] bf16
constexpr size_t WS_PB    = WS_WB  + (size_t)3 * CDIM * CDIM / 2;     // [768,768] bf16
constexpr size_t WS_QB    = WS_PB  + (size_t)CDIM * CDIM / 2;         // [BH,197,64] bf16
constexpr size_t WS_KB    = WS_QB  + (size_t)BH * NTOK * HD / 2;      // [BH,197,64] bf16
constexpr size_t WS_VTB   = WS_KB  + (size_t)BH * NTOK * HD / 2;      // [BH,64,224] bf16
constexpr size_t WS_AOB   = WS_VTB + (size_t)BH * HD * KPAD / 2;      // [MPAD,768] bf16
constexpr size_t WS_U     = WS_AOB + (size_t)MPAD * CDIM / 2;         // [BH,768] fp32
constexpr size_t WS_S     = WS_U   + (size_t)BH * CDIM;               // [BH,208] fp32

typedef __attribute__((ext_vector_type(8))) short short8;
typedef __attribute__((ext_vector_type(4))) float floatx4;

__device__ __forceinline__ ushort f2bf(float x) {
    __hip_bfloat16 h = __float2bfloat16(x);
    return *(ushort*)&h;
}

// async global->LDS, 16B per lane; LDS dest must be wave-uniform base + lane*16
__device__ __forceinline__ void load_lds16(const ushort* g, ushort* l) {
    __builtin_amdgcn_global_load_lds(
        (const __attribute__((address_space(1))) uint32_t*)(uintptr_t)g,
        (__attribute__((address_space(3))) uint32_t*)(uint32_t)(uintptr_t)l,
        16, 0, 0);
}

// ---------------------------------------------------------------------------
// Fused prep: fp32->bf16 casts (x padded to MPAD, qkv_w, proj_w) + exact fp32
// q0 projection + vtb pad-column zeroing. One dispatch instead of three.
// ---------------------------------------------------------------------------
constexpr int X_N4  = MROWS * CDIM / 4;         // valid x float4s
constexpr int X_NP4 = MPAD * CDIM / 4;          // padded x float4s
constexpr int W_N4  = 3 * CDIM * CDIM / 4;
constexpr int P_N4  = CDIM * CDIM / 4;
constexpr int CAST_TOTAL = X_NP4 + W_N4 + P_N4; // multiple of 256
constexpr int CASTB = CAST_TOTAL / 256;         // 11904
constexpr int Q0B   = BATCH * CDIM / 256;       // 192
constexpr int PADB  = BH * HD * 16 / 256;       // 3072 (16 uints = toks 192..223)
constexpr int PREPB = CASTB + Q0B + PADB;

__global__ __launch_bounds__(256) void prep_kernel(const float* __restrict__ x,
                                                   const float* __restrict__ qkv_w,
                                                   const float* __restrict__ proj_w,
                                                   const float* __restrict__ qkv_b,
                                                   ushort* __restrict__ xb,
                                                   ushort* __restrict__ wb,
                                                   ushort* __restrict__ pb,
                                                   float* __restrict__ q0,
                                                   ushort* __restrict__ vtb) {
    const int bk = blockIdx.x;
    const int t  = threadIdx.x;
    if (bk < CASTB) {
        const int i = bk * 256 + t;
        const float* src; ushort* dst; int j, valid;
        if (i < X_NP4)               { src = x;      dst = xb; j = i;               valid = (j < X_N4); }
        else if (i < X_NP4 + W_N4)   { src = qkv_w;  dst = wb; j = i - X_NP4;       valid = 1; }
        else                         { src = proj_w; dst = pb; j = i - X_NP4 - W_N4; valid = 1; }
        ushort4 h4 = make_ushort4(0, 0, 0, 0);
        if (valid) {
            float4 a = ((const float4*)src)[j];
            h4 = make_ushort4(f2bf(a.x), f2bf(a.y), f2bf(a.z), f2bf(a.w));
        }
        ((ushort4*)dst)[j] = h4;
    } else if (bk < CASTB + Q0B) {
        const int tid = (bk - CASTB) * 256 + t;
        const int b = tid / CDIM, c = tid - b * CDIM;
        const float* xr = x + (size_t)b * NTOK * CDIM;
        const float* wr = qkv_w + (size_t)c * CDIM;
        float s = 0.f;
        for (int k = 0; k < CDIM; k += 4) {
            float4 xv = *(const float4*)(xr + k);
            float4 wv = *(const float4*)(wr + k);
            s += xv.x * wv.x + xv.y * wv.y + xv.z * wv.z + xv.w * wv.w;
        }
        q0[tid] = s + qkv_b[c];
    } else {
        // zero vtb toks 192..223 per (bh,d) row (GEMM later rewrites 192..196)
        const int tid  = (bk - CASTB - Q0B) * 256 + t;
        const int rowd = tid >> 4;
        const int c    = tid & 15;
        ((uint*)vtb)[(size_t)rowd * (KPAD / 2) + 96 + c] = 0u;
    }
}

// ---------------------------------------------------------------------------
// u[bh, c] = sum_d q0[b, h*64+d] * Wk[h*64+d, c]   (Wk = qkv_w rows 768..1535)
// ---------------------------------------------------------------------------
__global__ __launch_bounds__(256) void u_kernel(const float* __restrict__ q0,
                                                const float* __restrict__ qkv_w,
                                                float* __restrict__ U) {
    const int bh = blockIdx.x;
    const int b  = bh / NH;
    const int h  = bh - b * NH;
    const int t  = threadIdx.x;

    __shared__ float q0s[HD];
    if (t < HD) q0s[t] = q0[(size_t)b * CDIM + h * HD + t];
    __syncthreads();

    const float* wk = qkv_w + (size_t)(CDIM + h * HD) * CDIM;
    float a0 = 0.f, a1 = 0.f, a2 = 0.f;
    for (int d = 0; d < HD; d++) {
        const float qd = q0s[d];
        const float* row = wk + (size_t)d * CDIM;
        a0 = fmaf(qd, row[t],       a0);
        a1 = fmaf(qd, row[t + 256], a1);
        a2 = fmaf(qd, row[t + 512], a2);
    }
    float* ub = U + (size_t)bh * CDIM;
    ub[t] = a0; ub[t + 256] = a1; ub[t + 512] = a2;
}

// ---------------------------------------------------------------------------
// S[bh, j] = u[bh,:] . x[b,j,:]   — 4 waves per block, one (j,b) per wave.
// ---------------------------------------------------------------------------
__global__ __launch_bounds__(256) void score_kernel(const float* __restrict__ x,
                                                    const float* __restrict__ U,
                                                    float* __restrict__ S) {
    const int wv   = threadIdx.x >> 6;
    const int lane = threadIdx.x & 63;
    const int j    = blockIdx.x * 4 + wv;
    const int b    = blockIdx.y;
    if (j >= NTOK) return;

    const float* xr = x + ((size_t)b * NTOK + j) * CDIM;
    float4 xv[3];
#pragma unroll
    for (int i = 0; i < 3; i++) xv[i] = *(const float4*)(xr + lane * 4 + i * 256);

    for (int h = 0; h < NH; h++) {
        const float* ur = U + (size_t)(b * NH + h) * CDIM;
        float s = 0.f;
#pragma unroll
        for (int i = 0; i < 3; i++) {
            float4 uv = *(const float4*)(ur + lane * 4 + i * 256);
            s += xv[i].x * uv.x + xv[i].y * uv.y + xv[i].z * uv.z + xv[i].w * uv.w;
        }
#pragma unroll
        for (int off = 32; off >= 1; off >>= 1) s += __shfl_xor(s, off);
        if (lane == 0) S[(size_t)(b * NH + h) * SPAD + j] = s;
    }
}

// ---------------------------------------------------------------------------
// 128x128 / BK=32 / 4-wave bf16 MFMA GEMM with DEPTH-3 pipelined staging:
// 3 LDS buffers (48 KiB), tiles prefetched 3 ahead via global_load_lds,
// counted s_waitcnt vmcnt(8) (never 0 until tail) so 2 full iterations
// (~680cy) of load latency are covered — the 1-deep __syncthreads structure
// exposed L3/L2-thrash latency (~400-900cy) every iteration (R0-R4 all
// ~95-116us regardless of inner-loop phasing).
// Race ledger: stage(kt+3 -> buf[kt%3]) is issued only after barrier #2,
// which all waves reach only after lgkmcnt(0) completes their ds_reads of
// that buffer; per-wave vmcnt(8) before barrier #1 guarantees tile kt is
// LDS-resident for all waves. sched_barrier(0) after lgkmcnt per rule #18.
// MODE 0: fp32 row-major O0f[Mvalid, N].
// MODE 1: q -> O0q[bh][tok][64], k -> O1k[bh][tok][64] (direct scatter);
//         v -> O2vt[bh][d][KPAD] via in-LDS 64x128 transpose (no separate
//         transpose kernel; pad cols zeroed by prep_kernel).
// ---------------------------------------------------------------------------
template <int MODE, int NCOLT>
__global__ __launch_bounds__(256, 3) void mfma_gemm128(
    const ushort* __restrict__ A, const ushort* __restrict__ W,
    const float* __restrict__ bias,
    float* __restrict__ O0f, ushort* __restrict__ O0q,
    ushort* __restrict__ O1k, ushort* __restrict__ O2vt,
    int Mvalid, int N) {
    constexpr int K    = CDIM;              // 768
    constexpr int BK   = 32;
    constexpr int NTK  = K / BK;            // 24 (divisible by 3)
    constexpr int BUFU = 128 * BK;          // 4096 ushorts = 8 KiB
    __shared__ ushort smem[6 * BUFU];       // 48 KiB: A0 A1 A2 B0 B1 B2

    const int t    = threadIdx.x;
    const int lane = t & 63;
    const int w    = t >> 6;
    const int wm   = (w >> 1) * 64;         // M-half of tile
    const int wn   = (w & 1) * 64;          // N-half of tile
    const int fr   = lane & 15;
    const int fq   = lane >> 4;             // 0..3

    // bijective XCD-aware swizzle (m204): contiguous wgid chunk per XCD
    int row, col;
    {
        constexpr int nwg = NROWT * NCOLT;
        constexpr int q = nwg >> 3, r = nwg & 7;
        const int xcd = blockIdx.x & 7, lin = blockIdx.x >> 3;
        const int wg = (xcd < r ? xcd * (q + 1) : r * (q + 1) + (xcd - r) * q) + lin;
        row = wg / NCOLT; col = wg - row * NCOLT;
    }
    const int rowBase = row * 128;
    const int colBase = col * 128;

    // stage one 128x32 tile (8 KB), linear layout (no swizzle: at BK=32 the
    // 64B row spans only 16 banks, XOR can't fix the 4-way aliasing and
    // R0 vs R4 measured it neutral)
    auto stage = [&](const ushort* __restrict__ G, ushort* dst, int grow0, int kt) {
#pragma unroll
        for (int i = 0; i < 2; ++i) {
            const int l  = i * 256 + t;
            const int rl = l >> 2;                       // row (4 thr/row)
            load_lds16(G + (size_t)(grow0 + rl) * K + kt * BK + (l & 3) * 8,
                       dst + l * 8);
        }
    };

    floatx4 acc[4][4];
#pragma unroll
    for (int i = 0; i < 4; ++i)
#pragma unroll
        for (int j = 0; j < 4; ++j)
#pragma unroll
            for (int r2 = 0; r2 < 4; ++r2) acc[i][j][r2] = 0.f;

    const int s0off = fq * 8;                // 16B slot within row

    // prologue: tiles 0,1,2 -> bufs 0,1,2 (12 loads/thread outstanding)
    stage(A, smem + 0 * BUFU, rowBase, 0); stage(W, smem + 3 * BUFU, colBase, 0);
    stage(A, smem + 1 * BUFU, rowBase, 1); stage(W, smem + 4 * BUFU, colBase, 1);
    stage(A, smem + 2 * BUFU, rowBase, 2); stage(W, smem + 5 * BUFU, colBase, 2);

    auto iter = [&](int kt, int bi) {
        if (kt < NTK - 2)       asm volatile("s_waitcnt vmcnt(8)" ::: "memory");
        else if (kt == NTK - 2) asm volatile("s_waitcnt vmcnt(4)" ::: "memory");
        else                    asm volatile("s_waitcnt vmcnt(0)" ::: "memory");
        __builtin_amdgcn_s_barrier();               // tile kt resident (all waves)
        asm volatile("" ::: "memory");

        const ushort* pa = smem + bi * BUFU + (wm + fr) * BK;
        const ushort* pb = smem + (3 + bi) * BUFU + (wn + fr) * BK;
        short8 af[4], bf[4];
#pragma unroll
        for (int i = 0; i < 4; ++i) {
            af[i] = *(const short8*)(pa + i * 512 + s0off);
            bf[i] = *(const short8*)(pb + i * 512 + s0off);
        }
        asm volatile("s_waitcnt lgkmcnt(0)" ::: "memory");
        __builtin_amdgcn_sched_barrier(0);
        __builtin_amdgcn_s_barrier();               // all reads of buf bi done
        asm volatile("" ::: "memory");
        if (kt + 3 < NTK) {                         // refill buf bi with tile kt+3
            stage(A, smem + bi * BUFU,       rowBase, kt + 3);
            stage(W, smem + (3 + bi) * BUFU, colBase, kt + 3);
        }
#pragma unroll
        for (int i = 0; i < 4; ++i)
#pragma unroll
            for (int j = 0; j < 4; ++j)
                acc[i][j] = __builtin_amdgcn_mfma_f32_16x16x32_bf16(
                    af[i], bf[j], acc[i][j], 0, 0, 0);
    };

    for (int k0 = 0; k0 < NTK; k0 += 3) {
        iter(k0, 0); iter(k0 + 1, 1); iter(k0 + 2, 2);
    }

    // ---- epilogue: C/D layout col(n)=lane&15, row(m)=(lane>>4)*4+reg ----
    if (MODE == 0) {
#pragma unroll
        for (int j = 0; j < 4; ++j) {
            const int nn = colBase + wn + j * 16 + fr;
            const float bq = bias[nn];
#pragma unroll
            for (int i = 0; i < 4; ++i) {
                const int mb = rowBase + wm + i * 16 + fq * 4;
#pragma unroll
                for (int r2 = 0; r2 < 4; ++r2) {
                    const int mm = mb + r2;
                    if (mm < Mvalid) O0f[(size_t)mm * N + nn] = acc[i][j][r2] + bq;
                }
            }
        }
    } else {
        const int which = colBase / CDIM;          // 0=q 1=k 2=v, block-uniform
        if (which < 2) {
            ushort* O = (which == 0) ? O0q : O1k;
#pragma unroll
            for (int j = 0; j < 4; ++j) {
                const int nn = colBase + wn + j * 16 + fr;
                const float bq = bias[nn];
                const int nc = nn - which * CDIM;
                const int h  = nc >> 6;
                const int d  = nc & 63;
#pragma unroll
                for (int i = 0; i < 4; ++i) {
                    const int mb = rowBase + wm + i * 16 + fq * 4;
#pragma unroll
                    for (int r2 = 0; r2 < 4; ++r2) {
                        const int mm = mb + r2;
                        if (mm < Mvalid) {
                            const int b   = mm / NTOK;
                            const int tok = mm - b * NTOK;
                            O[((size_t)(b * NH + h) * NTOK + tok) * HD + d] =
                                f2bf(acc[i][j][r2] + bq);
                        }
                    }
                }
            }
        } else {
            // v: in-LDS transpose, write Vt[bh][d][KPAD] directly
            const int c0  = colBase - 2 * CDIM;    // 0..640, multiple of 128
            const int h0  = c0 >> 6;
            ushort* T = smem;                       // [64][130] = 16.6 KiB
            const int mhw = wm >> 6;                // this wave's M-half
#pragma unroll
            for (int mh = 0; mh < 2; ++mh) {
                __syncthreads();
                if (mhw == mh) {
#pragma unroll
                    for (int j = 0; j < 4; ++j) {
                        const int ncl = wn + j * 16 + fr;          // 0..127
                        const float bq = bias[colBase + ncl];
#pragma unroll
                        for (int i = 0; i < 4; ++i)
#pragma unroll
                            for (int r2 = 0; r2 < 4; ++r2)
                                T[(i * 16 + fq * 4 + r2) * 130 + ncl] =
                                    f2bf(acc[i][j][r2] + bq);
                    }
                }
                __syncthreads();
                const int mmRow = rowBase + mh * 64 + lane;
                if (mmRow < Mvalid) {
                    const int bb  = mmRow / NTOK;
                    const int tok = mmRow - bb * NTOK;
                    ushort* vbase = O2vt + ((size_t)(bb * NH + h0) * HD) * KPAD + tok;
#pragma unroll
                    for (int s2 = 0; s2 < 32; ++s2) {
                        const int dd = w * 32 + s2;                // 0..127
                        vbase[(size_t)dd * KPAD] = T[lane * 130 + dd];
                    }
                }
            }
        }
    }
}

// ---------------------------------------------------------------------------
// MFMA flash attention: one wave (64 threads) per (q-tile, b*h).
// S^T = K.Q^T so queries sit in C-columns; online softmax per-lane + two
// shfl_xor quad-reduces. P via 1KB LDS roundtrip; PV uses transposed-V frags.
// ---------------------------------------------------------------------------
__global__ __launch_bounds__(64) void attn_mfma_kernel(const ushort* __restrict__ Qb,
                                                       const ushort* __restrict__ Kb,
                                                       const ushort* __restrict__ Vtb,
                                                       ushort* __restrict__ AOb) {
    const int qt = blockIdx.x;          // 0..12
    const int bh = blockIdx.y;          // 0..767
    const int b  = bh / NH;
    const int h  = bh - b * NH;
    const int lane = threadIdx.x;
    const int qc   = lane & 15;
    const int quad = lane >> 4;

    __shared__ ushort Pl[16][32];
    __shared__ float  alf[16], lf[16];

    const ushort* Qh = Qb  + (size_t)bh * NTOK * HD;
    const ushort* Kh = Kb  + (size_t)bh * NTOK * HD;
    const ushort* Vh = Vtb + (size_t)bh * HD * KPAD;

    const int qrow = min(qt * 16 + qc, NTOK - 1);
    const short8 qf0 = *(const short8*)(Qh + (size_t)qrow * HD + quad * 8);
    const short8 qf1 = *(const short8*)(Qh + (size_t)qrow * HD + 32 + quad * 8);

    floatx4 o[4];
#pragma unroll
    for (int s = 0; s < 4; s++)
#pragma unroll
        for (int r = 0; r < 4; r++) o[s][r] = 0.f;
    float m = -INFINITY, l = 0.f;

    for (int c0 = 0; c0 < NTOK; c0 += 32) {
        const int kr0 = min(c0 + qc, NTOK - 1);
        const int kr1 = min(c0 + 16 + qc, NTOK - 1);
        short8 kf00 = *(const short8*)(Kh + (size_t)kr0 * HD + quad * 8);
        short8 kf01 = *(const short8*)(Kh + (size_t)kr0 * HD + 32 + quad * 8);
        short8 kf10 = *(const short8*)(Kh + (size_t)kr1 * HD + quad * 8);
        short8 kf11 = *(const short8*)(Kh + (size_t)kr1 * HD + 32 + quad * 8);

        floatx4 s0 = {0.f, 0.f, 0.f, 0.f}, s1 = {0.f, 0.f, 0.f, 0.f};
        s0 = __builtin_amdgcn_mfma_f32_16x16x32_bf16(kf00, qf0, s0, 0, 0, 0);
        s0 = __builtin_amdgcn_mfma_f32_16x16x32_bf16(kf01, qf1, s0, 0, 0, 0);
        s1 = __builtin_amdgcn_mfma_f32_16x16x32_bf16(kf10, qf0, s1, 0, 0, 0);
        s1 = __builtin_amdgcn_mfma_f32_16x16x32_bf16(kf11, qf1, s1, 0, 0, 0);

        float sv[8];
        float mloc = -INFINITY;
#pragma unroll
        for (int r = 0; r < 4; r++) {
            const int key0 = c0 + quad * 4 + r;
            const int key1 = key0 + 16;
            sv[r]     = (key0 < NTOK) ? s0[r] * 0.125f : -1e30f;
            sv[4 + r] = (key1 < NTOK) ? s1[r] * 0.125f : -1e30f;
            mloc = fmaxf(mloc, fmaxf(sv[r], sv[4 + r]));
        }
        mloc = fmaxf(mloc, __shfl_xor(mloc, 16));
        mloc = fmaxf(mloc, __shfl_xor(mloc, 32));
        const float mnew  = fmaxf(m, mloc);
        const float alpha = __expf(m - mnew);
        float p[8], ps = 0.f;
#pragma unroll
        for (int i = 0; i < 8; i++) { p[i] = __expf(sv[i] - mnew); ps += p[i]; }
        ps += __shfl_xor(ps, 16);
        ps += __shfl_xor(ps, 32);
        l = l * alpha + ps;
        m = mnew;

#pragma unroll
        for (int r = 0; r < 4; r++) {
            Pl[qc][quad * 4 + r]      = f2bf(p[r]);
            Pl[qc][16 + quad * 4 + r] = f2bf(p[4 + r]);
        }
        if (quad == 0) alf[qc] = alpha;
        __syncthreads();

        float ar[4];
#pragma unroll
        for (int r = 0; r < 4; r++) ar[r] = alf[quad * 4 + r];
#pragma unroll
        for (int s = 0; s < 4; s++)
#pragma unroll
            for (int r = 0; r < 4; r++) o[s][r] *= ar[r];

        const short8 pf = *(const short8*)&Pl[qc][quad * 8];
#pragma unroll
        for (int s = 0; s < 4; s++) {
            const short8 vf = *(const short8*)(Vh + (size_t)(s * 16 + qc) * KPAD + c0 + quad * 8);
            o[s] = __builtin_amdgcn_mfma_f32_16x16x32_bf16(pf, vf, o[s], 0, 0, 0);
        }
        __syncthreads();
    }

    if (quad == 0) lf[qc] = l;
    __syncthreads();

#pragma unroll
    for (int r = 0; r < 4; r++) {
        const int tok = qt * 16 + quad * 4 + r;
        if (tok >= NTOK) continue;
        const float inv = 1.f / lf[quad * 4 + r];
        ushort* dst = AOb + ((size_t)(b * NTOK + tok)) * CDIM + h * HD;
#pragma unroll
        for (int s = 0; s < 4; s++) dst[s * 16 + qc] = f2bf(o[s][r] * inv);
    }
}

// ---------------------------------------------------------------------------
// Fused cls softmax (per head, exact fp32) + head-average + exact top-137
// (stable descending) + cls output. One block per batch; replaces
// cls_softmax + cls_mean + topk (2 dispatches and the clsph roundtrip).
// ---------------------------------------------------------------------------
__global__ __launch_bounds__(256) void topk_fused_kernel(const float* __restrict__ S,
                                                         const float* __restrict__ q0,
                                                         const float* __restrict__ qkv_b,
                                                         int* __restrict__ idxI,
                                                         float* __restrict__ idxOut,
                                                         float* __restrict__ outCls) {
    const int b    = blockIdx.x;
    const int t    = threadIdx.x;
    const int lane = t & 63;
    const int w    = t >> 6;

    __shared__ float qbv[NH];
    __shared__ float redm[4], reds[4];
    __shared__ float vsh[NTOK - 1];

    if (w == 0) {
        for (int h = 0; h < NH; ++h) {
            float p = q0[(size_t)b * CDIM + h * HD + lane] * qkv_b[CDIM + h * HD + lane];
#pragma unroll
            for (int off = 32; off >= 1; off >>= 1) p += __shfl_xor(p, off);
            if (lane == 0) qbv[h] = p;
        }
    }
    __syncthreads();

    float macc = 0.f;
    for (int h = 0; h < NH; ++h) {
        const float qb = qbv[h];
        const float sv = (t < NTOK) ? (S[(size_t)(b * NH + h) * SPAD + t] + qb) * 0.125f
                                    : -INFINITY;
        float mloc = sv;
#pragma unroll
        for (int off = 32; off >= 1; off >>= 1) mloc = fmaxf(mloc, __shfl_xor(mloc, off));
        if (lane == 0) redm[w] = mloc;
        __syncthreads();
        const float mx = fmaxf(fmaxf(redm[0], redm[1]), fmaxf(redm[2], redm[3]));
        const float p = (t < NTOK) ? expf(sv - mx) : 0.f;
        float ls = p;
#pragma unroll
        for (int off = 32; off >= 1; off >>= 1) ls += __shfl_xor(ls, off);
        if (lane == 0) reds[w] = ls;
        __syncthreads();
        const float denom = (reds[0] + reds[1]) + (reds[2] + reds[3]);
        macc += p / denom;
        __syncthreads();                  // protect redm/reds for next h
    }

    if (t >= 1 && t < NTOK) {
        const float val = macc * (1.f / 12.f);
        vsh[t - 1] = val;
        outCls[(size_t)b * (NTOK - 1) + (t - 1)] = val;
    }
    __syncthreads();

    if (t < NTOK - 1) {
        const float vi = vsh[t];
        int rank = 0;
        for (int j = 0; j < NTOK - 1; j++) {
            const float vj = vsh[j];
            rank += (vj > vi) || (vj == vi && j < t);
        }
        if (rank < LEFT) {
            idxI[b * LEFT + rank]   = t;
            idxOut[b * LEFT + rank] = (float)t;
        }
    }
}

// index = broadcast idx over channel dim, float4-vectorized (CDIM%4==0)
__global__ void fill_index_kernel(const int* __restrict__ idxI,
                                  float* __restrict__ dst) {
    int tid = blockIdx.x * 256 + threadIdx.x;
    constexpr int C4 = CDIM / 4;
    if (tid >= BATCH * LEFT * C4) return;
    float v = (float)idxI[tid / C4];
    ((float4*)dst)[tid] = make_float4(v, v, v, v);
}

extern "C" void kernel_launch(void* const* d_in, const int* in_sizes, int n_in,
                              void* d_out, int out_size, void* d_ws, size_t ws_size,
                              hipStream_t stream) {
    const float* x      = (const float*)d_in[0];
    const float* qkv_w  = (const float*)d_in[1];  // [2304,768]
    const float* qkv_b  = (const float*)d_in[2];  // [2304]
    const float* proj_w = (const float*)d_in[3];  // [768,768]
    const float* proj_b = (const float*)d_in[4];  // [768]
    float* out = (float*)d_out;

    float*  ws    = (float*)d_ws;
    int*    idxi  = (int*)(ws + WS_IDXI);
    float*  q0    = ws + WS_Q0;
    ushort* xb    = (ushort*)(ws + WS_XB);
    ushort* wb    = (ushort*)(ws + WS_WB);
    ushort* pb    = (ushort*)(ws + WS_PB);
    ushort* qb    = (ushort*)(ws + WS_QB);
    ushort* kb    = (ushort*)(ws + WS_KB);
    ushort* vtb   = (ushort*)(ws + WS_VTB);
    ushort* aob   = (ushort*)(ws + WS_AOB);
    float*  U     = ws + WS_U;
    float*  S     = ws + WS_S;

    // 1) fused prep: casts + exact q0 + vtb pad zeroing
    prep_kernel<<<PREPB, 256, 0, stream>>>(x, qkv_w, proj_w, qkv_b,
                                           xb, wb, pb, q0, vtb);

    // 2) Exact fp32 cls-score side path (top-k precision domain)
    u_kernel<<<BH, 256, 0, stream>>>(q0, qkv_w, U);
    score_kernel<<<dim3((NTOK + 3) / 4, BATCH), 256, 0, stream>>>(x, U, S);

    // 3) QKV projection (depth-3 pipelined MFMA) + q/k scatter + fused v-transpose
    mfma_gemm128<1, 18><<<NROWT * 18, 256, 0, stream>>>(
        xb, wb, qkv_b, nullptr, qb, kb, vtb, MROWS, 3 * CDIM);

    // 4) MFMA flash attention -> bf16 pre-proj out
    attn_mfma_kernel<<<dim3(13, BH), 64, 0, stream>>>(qb, kb, vtb, aob);

    // 5) Output projection (depth-3 pipelined MFMA) -> fp32 out
    mfma_gemm128<0, 6><<<NROWT * 6, 256, 0, stream>>>(
        aob, pb, proj_b, out + OUT_OFF_OUT, nullptr, nullptr, nullptr,
        MROWS, CDIM);

    // 6) Fused cls softmax + head-average + exact top-137 + cls output
    topk_fused_kernel<<<BATCH, 256, 0, stream>>>(S, q0, qkv_b, idxi,
                                                 out + OUT_OFF_IDX,
                                                 out + OUT_OFF_CLS);

    // 7) Broadcast indices over channels (float4)
    fill_index_kernel<<<((size_t)BATCH * LEFT * (CDIM / 4) + 255) / 256, 256, 0, stream>>>(
        idxi, out + OUT_OFF_INDEX);
}

// Round 6
// 368.233 us; speedup vs baseline: 1.2822x; 1.2822x over previous
//
#include <hip/hip_runtime.h>
#include <hip/hip_bf16.h>
#include <stdint.h>

// Problem constants
constexpr int BATCH = 64;
constexpr int NTOK  = 197;
constexpr int CDIM  = 768;
constexpr int NH    = 12;
constexpr int HD    = 64;
constexpr int MROWS = BATCH * NTOK;        // 12608
constexpr int MPAD  = 12800;               // 100 * 128 (GEMM row tiles)
constexpr int NROWT = MPAD / 128;          // 100
constexpr int LEFT  = 137;                 // int(0.7 * 196)
constexpr int KPAD  = 224;                 // keys padded (7 * 32)
constexpr int BH    = BATCH * NH;          // 768
constexpr int SPAD  = 208;                 // score row stride

// Output layout (flat float32, concatenated in return order)
constexpr size_t OUT_OFF_OUT   = 0;                                   // [64,197,768]
constexpr size_t OUT_OFF_INDEX = (size_t)BATCH * NTOK * CDIM;         // [64,137,768]
constexpr size_t OUT_OFF_IDX   = OUT_OFF_INDEX + (size_t)BATCH * LEFT * CDIM; // [64,137]
constexpr size_t OUT_OFF_CLS   = OUT_OFF_IDX + (size_t)BATCH * LEFT;  // [64,196]

// Workspace layout (float units; bf16 regions counted as elems/2)
constexpr size_t WS_CLSPH = 0;                                        // (unused, kept for layout)
constexpr size_t WS_CLSF  = WS_CLSPH + (size_t)BH * (NTOK - 1);
constexpr size_t WS_IDXI  = WS_CLSF  + (size_t)BATCH * (NTOK - 1);
constexpr size_t WS_Q0    = WS_IDXI  + (size_t)BATCH * LEFT;          // [64,768]
constexpr size_t WS_XB    = WS_Q0  + (size_t)BATCH * CDIM;            // [MPAD,768] bf16
constexpr size_t WS_WB    = WS_XB  + (size_t)MPAD * CDIM / 2;         // [2304,768] bf16
constexpr size_t WS_PB    = WS_WB  + (size_t)3 * CDIM * CDIM / 2;     // [768,768] bf16
constexpr size_t WS_QB    = WS_PB  + (size_t)CDIM * CDIM / 2;         // [BH,197,64] bf16
constexpr size_t WS_KB    = WS_QB  + (size_t)BH * NTOK * HD / 2;      // [BH,197,64] bf16
constexpr size_t WS_VTB   = WS_KB  + (size_t)BH * NTOK * HD / 2;      // [BH,64,224] bf16
constexpr size_t WS_AOB   = WS_VTB + (size_t)BH * HD * KPAD / 2;      // [MPAD,768] bf16
constexpr size_t WS_U     = WS_AOB + (size_t)MPAD * CDIM / 2;         // [BH,768] fp32
constexpr size_t WS_S     = WS_U   + (size_t)BH * CDIM;               // [BH,208] fp32

typedef __attribute__((ext_vector_type(8))) short short8;
typedef __attribute__((ext_vector_type(4))) float floatx4;

__device__ __forceinline__ ushort f2bf(float x) {
    __hip_bfloat16 h = __float2bfloat16(x);
    return *(ushort*)&h;
}

// async global->LDS, 16B per lane; LDS dest must be wave-uniform base + lane*16
__device__ __forceinline__ void load_lds16(const ushort* g, ushort* l) {
    __builtin_amdgcn_global_load_lds(
        (const __attribute__((address_space(1))) uint32_t*)(uintptr_t)g,
        (__attribute__((address_space(3))) uint32_t*)(uint32_t)(uintptr_t)l,
        16, 0, 0);
}

// ---------------------------------------------------------------------------
// Fused fp32 -> bf16 cast of x (padded to MPAD rows), qkv_w, proj_w.
// ---------------------------------------------------------------------------
constexpr int X_N4  = MROWS * CDIM / 4;         // valid x float4s
constexpr int X_NP4 = MPAD * CDIM / 4;          // padded x float4s
constexpr int W_N4  = 3 * CDIM * CDIM / 4;
constexpr int P_N4  = CDIM * CDIM / 4;
constexpr int CAST_TOTAL = X_NP4 + W_N4 + P_N4; // multiple of 256

__global__ __launch_bounds__(256) void cast_all_kernel(const float* __restrict__ x,
                                                       const float* __restrict__ qkv_w,
                                                       const float* __restrict__ proj_w,
                                                       ushort* __restrict__ xb,
                                                       ushort* __restrict__ wb,
                                                       ushort* __restrict__ pb) {
    int i = blockIdx.x * 256 + threadIdx.x;
    const float* src;
    ushort* dst;
    int j, valid;
    if (i < X_NP4) {
        src = x; dst = xb; j = i; valid = (j < X_N4);
    } else if (i < X_NP4 + W_N4) {
        src = qkv_w; dst = wb; j = i - X_NP4; valid = 1;
    } else if (i < CAST_TOTAL) {
        src = proj_w; dst = pb; j = i - X_NP4 - W_N4; valid = 1;
    } else {
        return;
    }
    ushort4 h4 = make_ushort4(0, 0, 0, 0);
    if (valid) {
        float4 a = ((const float4*)src)[j];
        h4 = make_ushort4(f2bf(a.x), f2bf(a.y), f2bf(a.z), f2bf(a.w));
    }
    ((ushort4*)dst)[j] = h4;
}

// ---------------------------------------------------------------------------
// Exact fp32 q row-0 projection, wave-parallel over K:
// q0[b,c] = x[b,0,:] . qkv_w[c,:] + qkv_b[c].
// One wave per (b,c): 64 lanes split the 768-dim (coalesced 16B/lane reads of
// the SAME w-row) + shfl tree reduce. Replaces the per-thread row-scan q0
// (uncoalesced 3KB strides, <1 block/CU -> ~90-180us measured in R5's prep).
// ---------------------------------------------------------------------------
__global__ __launch_bounds__(256) void q0_kernel(const float* __restrict__ x,
                                                 const float* __restrict__ qkv_w,
                                                 const float* __restrict__ qkv_b,
                                                 float* __restrict__ q0) {
    const int wv   = threadIdx.x >> 6;
    const int lane = threadIdx.x & 63;
    constexpr int CG = CDIM / 4;            // 192 c-groups of 4
    const int b = blockIdx.x / CG;
    const int c = (blockIdx.x - b * CG) * 4 + wv;

    const float* xr = x + (size_t)b * NTOK * CDIM;
    const float* wr = qkv_w + (size_t)c * CDIM;
    float s = 0.f;
#pragma unroll
    for (int i = 0; i < 3; i++) {
        float4 xv = *(const float4*)(xr + lane * 4 + i * 256);
        float4 wv4 = *(const float4*)(wr + lane * 4 + i * 256);
        s += xv.x * wv4.x + xv.y * wv4.y + xv.z * wv4.z + xv.w * wv4.w;
    }
#pragma unroll
    for (int off = 32; off >= 1; off >>= 1) s += __shfl_xor(s, off);
    if (lane == 0) q0[(size_t)b * CDIM + c] = s + qkv_b[c];
}

// ---------------------------------------------------------------------------
// u[bh, c] = sum_d q0[b, h*64+d] * Wk[h*64+d, c]   (Wk = qkv_w rows 768..1535)
// ---------------------------------------------------------------------------
__global__ __launch_bounds__(256) void u_kernel(const float* __restrict__ q0,
                                                const float* __restrict__ qkv_w,
                                                float* __restrict__ U) {
    const int bh = blockIdx.x;
    const int b  = bh / NH;
    const int h  = bh - b * NH;
    const int t  = threadIdx.x;

    __shared__ float q0s[HD];
    if (t < HD) q0s[t] = q0[(size_t)b * CDIM + h * HD + t];
    __syncthreads();

    const float* wk = qkv_w + (size_t)(CDIM + h * HD) * CDIM;
    float a0 = 0.f, a1 = 0.f, a2 = 0.f;
    for (int d = 0; d < HD; d++) {
        const float qd = q0s[d];
        const float* row = wk + (size_t)d * CDIM;
        a0 = fmaf(qd, row[t],       a0);
        a1 = fmaf(qd, row[t + 256], a1);
        a2 = fmaf(qd, row[t + 512], a2);
    }
    float* ub = U + (size_t)bh * CDIM;
    ub[t] = a0; ub[t + 256] = a1; ub[t + 512] = a2;
}

// ---------------------------------------------------------------------------
// S[bh, j] = u[bh,:] . x[b,j,:]   — 4 waves per block, one (j,b) per wave.
// ---------------------------------------------------------------------------
__global__ __launch_bounds__(256) void score_kernel(const float* __restrict__ x,
                                                    const float* __restrict__ U,
                                                    float* __restrict__ S) {
    const int wv   = threadIdx.x >> 6;
    const int lane = threadIdx.x & 63;
    const int j    = blockIdx.x * 4 + wv;
    const int b    = blockIdx.y;
    if (j >= NTOK) return;

    const float* xr = x + ((size_t)b * NTOK + j) * CDIM;
    float4 xv[3];
#pragma unroll
    for (int i = 0; i < 3; i++) xv[i] = *(const float4*)(xr + lane * 4 + i * 256);

    for (int h = 0; h < NH; h++) {
        const float* ur = U + (size_t)(b * NH + h) * CDIM;
        float s = 0.f;
#pragma unroll
        for (int i = 0; i < 3; i++) {
            float4 uv = *(const float4*)(ur + lane * 4 + i * 256);
            s += xv[i].x * uv.x + xv[i].y * uv.y + xv[i].z * uv.z + xv[i].w * uv.w;
        }
#pragma unroll
        for (int off = 32; off >= 1; off >>= 1) s += __shfl_xor(s, off);
        if (lane == 0) S[(size_t)(b * NH + h) * SPAD + j] = s;
    }
}

// ---------------------------------------------------------------------------
// 128x128 / BK=32 / 4-wave bf16 MFMA GEMM — the R4-measured m97 geometry:
// 32 KiB LDS double-buffer + __launch_bounds__(256,4) -> 4 blocks/CU.
// (R5's depth-3 pipeline + fused v-transpose were unmeasurable under the
// 180us prep and the total regressed — reverted to this measured version.)
// - T2 XOR swizzle (4 slots/row): phys 16B slot = logical ^ (row&3).
// - bijective XCD-aware block swizzle for A-panel L2 locality.
// MODE 0: fp32 row-major O0f[Mvalid, N].
// MODE 1: qkv split (bf16): q -> O0q[bh][tok][64], k -> O1k[bh][tok][64],
//         v -> DENSE O2vd[m][768] (32B-segment stores; transposed later).
// ---------------------------------------------------------------------------
template <int MODE, int NCOLT>
__global__ __launch_bounds__(256, 4) void mfma_gemm128(
    const ushort* __restrict__ A, const ushort* __restrict__ W,
    const float* __restrict__ bias,
    float* __restrict__ O0f, ushort* __restrict__ O0q,
    ushort* __restrict__ O1k, ushort* __restrict__ O2vd,
    int Mvalid, int N) {
    constexpr int K   = CDIM;               // 768
    constexpr int BK  = 32;
    constexpr int NTK = K / BK;             // 24
    __shared__ ushort sA[2 * 128 * BK];     // 16 KiB
    __shared__ ushort sB[2 * 128 * BK];     // 16 KiB

    const int t    = threadIdx.x;
    const int lane = t & 63;
    const int w    = t >> 6;
    const int wm   = (w >> 1) * 64;         // M-half of tile
    const int wn   = (w & 1) * 64;          // N-half of tile
    const int fr   = lane & 15;
    const int fq   = lane >> 4;             // 0..3
    const int f3   = lane & 3;              // == fr & 3

    // bijective XCD-aware swizzle (m204): contiguous wgid chunk per XCD
    int row, col;
    {
        constexpr int nwg = NROWT * NCOLT;
        constexpr int q = nwg >> 3, r = nwg & 7;
        const int xcd = blockIdx.x & 7, lin = blockIdx.x >> 3;
        const int wg = (xcd < r ? xcd * (q + 1) : r * (q + 1) + (xcd - r) * q) + lin;
        row = wg / NCOLT; col = wg - row * NCOLT;
    }
    const int rowBase = row * 128;
    const int colBase = col * 128;

    // stage one 128x32 tile (8 KB): linear LDS dest, inverse-swizzled source
    auto stage = [&](const ushort* __restrict__ G, ushort* dst, int grow0, int kt) {
#pragma unroll
        for (int i = 0; i < 2; ++i) {
            const int l  = i * 256 + t;
            const int rl = l >> 2;                       // row (4 thr/row)
            const int sl = (l & 3) ^ (rl & 3);           // swizzled 16B slot
            load_lds16(G + (size_t)(grow0 + rl) * K + kt * BK + sl * 8,
                       dst + l * 8);
        }
    };

    floatx4 acc[4][4];
#pragma unroll
    for (int i = 0; i < 4; ++i)
#pragma unroll
        for (int j = 0; j < 4; ++j)
#pragma unroll
            for (int r2 = 0; r2 < 4; ++r2) acc[i][j][r2] = 0.f;

    // read-side swizzled slot offset (ushort units): logical slot fq
    const int s0 = (fq ^ f3) * 8;

    // prologue: tile 0 -> buffer 0
    stage(A, sA, rowBase, 0);
    stage(W, sB, colBase, 0);

    for (int kt = 0; kt < NTK; ++kt) {
        __syncthreads();                     // drains vm+lgkm: buf[cur] ready,
                                             // buf[cur^1] reads complete
        const int cb = (kt & 1) << 12;       // current buffer (ushort offset)
        if (kt + 1 < NTK) {                  // prefetch next tile
            stage(A, sA + (cb ^ 4096), rowBase, kt + 1);
            stage(W, sB + (cb ^ 4096), colBase, kt + 1);
        }

        const ushort* pa = sA + cb + (wm + fr) * BK;
        const ushort* pb = sB + cb + (wn + fr) * BK;
        short8 af[4], bf[4];
#pragma unroll
        for (int i = 0; i < 4; ++i) {
            af[i] = *(const short8*)(pa + i * 512 + s0);
            bf[i] = *(const short8*)(pb + i * 512 + s0);
        }
#pragma unroll
        for (int i = 0; i < 4; ++i)
#pragma unroll
            for (int j = 0; j < 4; ++j)
                acc[i][j] = __builtin_amdgcn_mfma_f32_16x16x32_bf16(
                    af[i], bf[j], acc[i][j], 0, 0, 0);
    }

    // epilogue: C/D layout col(n)=lane&15, row(m)=(lane>>4)*4+reg
#pragma unroll
    for (int j = 0; j < 4; ++j) {
        const int nn = colBase + wn + j * 16 + fr;
        const float bq = bias[nn];
        if (MODE == 0) {
#pragma unroll
            for (int i = 0; i < 4; ++i) {
                const int mb = rowBase + wm + i * 16 + fq * 4;
#pragma unroll
                for (int r2 = 0; r2 < 4; ++r2) {
                    const int mm = mb + r2;
                    if (mm < Mvalid) O0f[(size_t)mm * N + nn] = acc[i][j][r2] + bq;
                }
            }
        } else {
            const int which = nn / CDIM;     // wave-uniform per col-tile
            const int nc    = nn - which * CDIM;
            const int h     = nc >> 6;
            const int d     = nc & 63;
#pragma unroll
            for (int i = 0; i < 4; ++i) {
                const int mb = rowBase + wm + i * 16 + fq * 4;
#pragma unroll
                for (int r2 = 0; r2 < 4; ++r2) {
                    const int mm = mb + r2;
                    if (mm < Mvalid) {
                        const int b   = mm / NTOK;
                        const int tok = mm - b * NTOK;
                        const int bh  = b * NH + h;
                        const ushort val = f2bf(acc[i][j][r2] + bq);
                        if (which == 0)      O0q[((size_t)bh * NTOK + tok) * HD + d] = val;
                        else if (which == 1) O1k[((size_t)bh * NTOK + tok) * HD + d] = val;
                        else                 O2vd[(size_t)mm * CDIM + nc] = val;  // dense
                    }
                }
            }
        }
    }
}

// ---------------------------------------------------------------------------
// Vd[b*197+tok][768] (dense v, bf16) -> Vtb[bh][d][KPAD] via LDS transpose.
// Coalesced 128B row reads, 448B row writes; zero-fills pad cols 197..223.
// ---------------------------------------------------------------------------
__global__ __launch_bounds__(256) void v_transpose_kernel(const ushort* __restrict__ Vd,
                                                          ushort* __restrict__ Vtb) {
    const int bh = blockIdx.x;             // 0..767
    const int b  = bh / NH;
    const int h  = bh - b * NH;
    const int t  = threadIdx.x;

    __shared__ ushort tile[HD][KPAD + 9];  // odd pad stride vs bank conflicts

    const int d  = t & 63;
    const int tt = t >> 6;                 // 0..3
    const ushort* src = Vd + (size_t)b * NTOK * CDIM + h * HD + d;
    for (int tok0 = 0; tok0 < KPAD; tok0 += 4) {
        const int tok = tok0 + tt;
        ushort v = 0;
        if (tok < NTOK) v = src[(size_t)tok * CDIM];
        tile[d][tok] = v;
    }
    __syncthreads();

    uint* dst = (uint*)(Vtb + (size_t)bh * HD * KPAD);
    constexpr int C2 = KPAD / 2;           // 112 u32 per d-row
    for (int idx = t; idx < HD * C2; idx += 256) {
        const int dd = idx / C2;
        const int c  = idx - dd * C2;
        const uint lo = tile[dd][2 * c];
        const uint hi = tile[dd][2 * c + 1];
        dst[dd * C2 + c] = lo | (hi << 16);
    }
}

// ---------------------------------------------------------------------------
// MFMA flash attention: one wave (64 threads) per (q-tile, b*h).
// S^T = K.Q^T so queries sit in C-columns; online softmax per-lane + two
// shfl_xor quad-reduces. P via 1KB LDS roundtrip; PV uses transposed-V frags.
// ---------------------------------------------------------------------------
__global__ __launch_bounds__(64) void attn_mfma_kernel(const ushort* __restrict__ Qb,
                                                       const ushort* __restrict__ Kb,
                                                       const ushort* __restrict__ Vtb,
                                                       ushort* __restrict__ AOb) {
    const int qt = blockIdx.x;          // 0..12
    const int bh = blockIdx.y;          // 0..767
    const int b  = bh / NH;
    const int h  = bh - b * NH;
    const int lane = threadIdx.x;
    const int qc   = lane & 15;
    const int quad = lane >> 4;

    __shared__ ushort Pl[16][32];
    __shared__ float  alf[16], lf[16];

    const ushort* Qh = Qb  + (size_t)bh * NTOK * HD;
    const ushort* Kh = Kb  + (size_t)bh * NTOK * HD;
    const ushort* Vh = Vtb + (size_t)bh * HD * KPAD;

    const int qrow = min(qt * 16 + qc, NTOK - 1);
    const short8 qf0 = *(const short8*)(Qh + (size_t)qrow * HD + quad * 8);
    const short8 qf1 = *(const short8*)(Qh + (size_t)qrow * HD + 32 + quad * 8);

    floatx4 o[4];
#pragma unroll
    for (int s = 0; s < 4; s++)
#pragma unroll
        for (int r = 0; r < 4; r++) o[s][r] = 0.f;
    float m = -INFINITY, l = 0.f;

    for (int c0 = 0; c0 < NTOK; c0 += 32) {
        const int kr0 = min(c0 + qc, NTOK - 1);
        const int kr1 = min(c0 + 16 + qc, NTOK - 1);
        short8 kf00 = *(const short8*)(Kh + (size_t)kr0 * HD + quad * 8);
        short8 kf01 = *(const short8*)(Kh + (size_t)kr0 * HD + 32 + quad * 8);
        short8 kf10 = *(const short8*)(Kh + (size_t)kr1 * HD + quad * 8);
        short8 kf11 = *(const short8*)(Kh + (size_t)kr1 * HD + 32 + quad * 8);

        floatx4 s0 = {0.f, 0.f, 0.f, 0.f}, s1 = {0.f, 0.f, 0.f, 0.f};
        s0 = __builtin_amdgcn_mfma_f32_16x16x32_bf16(kf00, qf0, s0, 0, 0, 0);
        s0 = __builtin_amdgcn_mfma_f32_16x16x32_bf16(kf01, qf1, s0, 0, 0, 0);
        s1 = __builtin_amdgcn_mfma_f32_16x16x32_bf16(kf10, qf0, s1, 0, 0, 0);
        s1 = __builtin_amdgcn_mfma_f32_16x16x32_bf16(kf11, qf1, s1, 0, 0, 0);

        float sv[8];
        float mloc = -INFINITY;
#pragma unroll
        for (int r = 0; r < 4; r++) {
            const int key0 = c0 + quad * 4 + r;
            const int key1 = key0 + 16;
            sv[r]     = (key0 < NTOK) ? s0[r] * 0.125f : -1e30f;
            sv[4 + r] = (key1 < NTOK) ? s1[r] * 0.125f : -1e30f;
            mloc = fmaxf(mloc, fmaxf(sv[r], sv[4 + r]));
        }
        mloc = fmaxf(mloc, __shfl_xor(mloc, 16));
        mloc = fmaxf(mloc, __shfl_xor(mloc, 32));
        const float mnew  = fmaxf(m, mloc);
        const float alpha = __expf(m - mnew);
        float p[8], ps = 0.f;
#pragma unroll
        for (int i = 0; i < 8; i++) { p[i] = __expf(sv[i] - mnew); ps += p[i]; }
        ps += __shfl_xor(ps, 16);
        ps += __shfl_xor(ps, 32);
        l = l * alpha + ps;
        m = mnew;

#pragma unroll
        for (int r = 0; r < 4; r++) {
            Pl[qc][quad * 4 + r]      = f2bf(p[r]);
            Pl[qc][16 + quad * 4 + r] = f2bf(p[4 + r]);
        }
        if (quad == 0) alf[qc] = alpha;
        __syncthreads();

        float ar[4];
#pragma unroll
        for (int r = 0; r < 4; r++) ar[r] = alf[quad * 4 + r];
#pragma unroll
        for (int s = 0; s < 4; s++)
#pragma unroll
            for (int r = 0; r < 4; r++) o[s][r] *= ar[r];

        const short8 pf = *(const short8*)&Pl[qc][quad * 8];
#pragma unroll
        for (int s = 0; s < 4; s++) {
            const short8 vf = *(const short8*)(Vh + (size_t)(s * 16 + qc) * KPAD + c0 + quad * 8);
            o[s] = __builtin_amdgcn_mfma_f32_16x16x32_bf16(pf, vf, o[s], 0, 0, 0);
        }
        __syncthreads();
    }

    if (quad == 0) lf[qc] = l;
    __syncthreads();

#pragma unroll
    for (int r = 0; r < 4; r++) {
        const int tok = qt * 16 + quad * 4 + r;
        if (tok >= NTOK) continue;
        const float inv = 1.f / lf[quad * 4 + r];
        ushort* dst = AOb + ((size_t)(b * NTOK + tok)) * CDIM + h * HD;
#pragma unroll
        for (int s = 0; s < 4; s++) dst[s * 16 + qc] = f2bf(o[s][r] * inv);
    }
}

// ---------------------------------------------------------------------------
// Fused cls softmax (per head, exact fp32) + head-average + exact top-137
// (stable descending) + cls output. One block per batch.
// ---------------------------------------------------------------------------
__global__ __launch_bounds__(256) void topk_fused_kernel(const float* __restrict__ S,
                                                         const float* __restrict__ q0,
                                                         const float* __restrict__ qkv_b,
                                                         int* __restrict__ idxI,
                                                         float* __restrict__ idxOut,
                                                         float* __restrict__ outCls) {
    const int b    = blockIdx.x;
    const int t    = threadIdx.x;
    const int lane = t & 63;
    const int w    = t >> 6;

    __shared__ float qbv[NH];
    __shared__ float redm[4], reds[4];
    __shared__ float vsh[NTOK - 1];

    if (w == 0) {
        for (int h = 0; h < NH; ++h) {
            float p = q0[(size_t)b * CDIM + h * HD + lane] * qkv_b[CDIM + h * HD + lane];
#pragma unroll
            for (int off = 32; off >= 1; off >>= 1) p += __shfl_xor(p, off);
            if (lane == 0) qbv[h] = p;
        }
    }
    __syncthreads();

    float macc = 0.f;
    for (int h = 0; h < NH; ++h) {
        const float qb = qbv[h];
        const float sv = (t < NTOK) ? (S[(size_t)(b * NH + h) * SPAD + t] + qb) * 0.125f
                                    : -INFINITY;
        float mloc = sv;
#pragma unroll
        for (int off = 32; off >= 1; off >>= 1) mloc = fmaxf(mloc, __shfl_xor(mloc, off));
        if (lane == 0) redm[w] = mloc;
        __syncthreads();
        const float mx = fmaxf(fmaxf(redm[0], redm[1]), fmaxf(redm[2], redm[3]));
        const float p = (t < NTOK) ? expf(sv - mx) : 0.f;
        float ls = p;
#pragma unroll
        for (int off = 32; off >= 1; off >>= 1) ls += __shfl_xor(ls, off);
        if (lane == 0) reds[w] = ls;
        __syncthreads();
        const float denom = (reds[0] + reds[1]) + (reds[2] + reds[3]);
        macc += p / denom;
        __syncthreads();                  // protect redm/reds for next h
    }

    if (t >= 1 && t < NTOK) {
        const float val = macc * (1.f / 12.f);
        vsh[t - 1] = val;
        outCls[(size_t)b * (NTOK - 1) + (t - 1)] = val;
    }
    __syncthreads();

    if (t < NTOK - 1) {
        const float vi = vsh[t];
        int rank = 0;
        for (int j = 0; j < NTOK - 1; j++) {
            const float vj = vsh[j];
            rank += (vj > vi) || (vj == vi && j < t);
        }
        if (rank < LEFT) {
            idxI[b * LEFT + rank]   = t;
            idxOut[b * LEFT + rank] = (float)t;
        }
    }
}

// index = broadcast idx over channel dim, float4-vectorized (CDIM%4==0)
__global__ void fill_index_kernel(const int* __restrict__ idxI,
                                  float* __restrict__ dst) {
    int tid = blockIdx.x * 256 + threadIdx.x;
    constexpr int C4 = CDIM / 4;
    if (tid >= BATCH * LEFT * C4) return;
    float v = (float)idxI[tid / C4];
    ((float4*)dst)[tid] = make_float4(v, v, v, v);
}

extern "C" void kernel_launch(void* const* d_in, const int* in_sizes, int n_in,
                              void* d_out, int out_size, void* d_ws, size_t ws_size,
                              hipStream_t stream) {
    const float* x      = (const float*)d_in[0];
    const float* qkv_w  = (const float*)d_in[1];  // [2304,768]
    const float* qkv_b  = (const float*)d_in[2];  // [2304]
    const float* proj_w = (const float*)d_in[3];  // [768,768]
    const float* proj_b = (const float*)d_in[4];  // [768]
    float* out = (float*)d_out;

    float*  ws    = (float*)d_ws;
    int*    idxi  = (int*)(ws + WS_IDXI);
    float*  q0    = ws + WS_Q0;
    ushort* xb    = (ushort*)(ws + WS_XB);
    ushort* wb    = (ushort*)(ws + WS_WB);
    ushort* pb    = (ushort*)(ws + WS_PB);
    ushort* qb    = (ushort*)(ws + WS_QB);
    ushort* kb    = (ushort*)(ws + WS_KB);
    ushort* vtb   = (ushort*)(ws + WS_VTB);
    ushort* aob   = (ushort*)(ws + WS_AOB);
    ushort* vd    = aob;   // dense-v staging aliases aob (free until attn runs)
    float*  U     = ws + WS_U;
    float*  S     = ws + WS_S;

    // 1) fused fp32 -> bf16 casts (x padded to MPAD, qkv_w, proj_w)
    cast_all_kernel<<<CAST_TOTAL / 256, 256, 0, stream>>>(x, qkv_w, proj_w, xb, wb, pb);

    // 2) Exact fp32 cls-score side path (top-k precision domain)
    q0_kernel<<<BATCH * (CDIM / 4), 256, 0, stream>>>(x, qkv_w, qkv_b, q0);
    u_kernel<<<BH, 256, 0, stream>>>(q0, qkv_w, U);
    score_kernel<<<dim3((NTOK + 3) / 4, BATCH), 256, 0, stream>>>(x, U, S);

    // 3) QKV projection (128²/BK32 MFMA, 4 blocks/CU) + q/k split, v dense
    mfma_gemm128<1, 18><<<NROWT * 18, 256, 0, stream>>>(
        xb, wb, qkv_b, nullptr, qb, kb, vd, MROWS, 3 * CDIM);

    // 3b) dense v -> transposed vtb (coalesced; zero-fills pad cols)
    v_transpose_kernel<<<BH, 256, 0, stream>>>(vd, vtb);

    // 4) MFMA flash attention -> bf16 pre-proj out (overwrites vd alias)
    attn_mfma_kernel<<<dim3(13, BH), 64, 0, stream>>>(qb, kb, vtb, aob);

    // 5) Output projection (128²/BK32 MFMA) -> fp32 out
    mfma_gemm128<0, 6><<<NROWT * 6, 256, 0, stream>>>(
        aob, pb, proj_b, out + OUT_OFF_OUT, nullptr, nullptr, nullptr,
        MROWS, CDIM);

    // 6) Fused cls softmax + head-average + exact top-137 + cls output
    topk_fused_kernel<<<BATCH, 256, 0, stream>>>(S, q0, qkv_b, idxi,
                                                 out + OUT_OFF_IDX,
                                                 out + OUT_OFF_CLS);

    // 7) Broadcast indices over channels (float4)
    fill_index_kernel<<<((size_t)BATCH * LEFT * (CDIM / 4) + 255) / 256, 256, 0, stream>>>(
        idxi, out + OUT_OFF_INDEX);
}

// Round 7
// 360.241 us; speedup vs baseline: 1.3106x; 1.0222x over previous
//
#include <hip/hip_runtime.h>
#include <hip/hip_bf16.h>
#include <stdint.h>

// Problem constants
constexpr int BATCH = 64;
constexpr int NTOK  = 197;
constexpr int CDIM  = 768;
constexpr int NH    = 12;
constexpr int HD    = 64;
constexpr int MROWS = BATCH * NTOK;        // 12608
constexpr int MPAD  = 12800;               // 100 * 128 (GEMM row tiles)
constexpr int NROWT = MPAD / 128;          // 100
constexpr int LEFT  = 137;                 // int(0.7 * 196)
constexpr int KPAD  = 224;                 // keys padded (7 * 32)
constexpr int BH    = BATCH * NH;          // 768
constexpr int SPAD  = 208;                 // score row stride

// Output layout (flat float32, concatenated in return order)
constexpr size_t OUT_OFF_OUT   = 0;                                   // [64,197,768]
constexpr size_t OUT_OFF_INDEX = (size_t)BATCH * NTOK * CDIM;         // [64,137,768]
constexpr size_t OUT_OFF_IDX   = OUT_OFF_INDEX + (size_t)BATCH * LEFT * CDIM; // [64,137]
constexpr size_t OUT_OFF_CLS   = OUT_OFF_IDX + (size_t)BATCH * LEFT;  // [64,196]

// Workspace layout (float units; bf16 regions counted as elems/2)
constexpr size_t WS_CLSPH = 0;                                        // (unused, kept for layout)
constexpr size_t WS_CLSF  = WS_CLSPH + (size_t)BH * (NTOK - 1);
constexpr size_t WS_IDXI  = WS_CLSF  + (size_t)BATCH * (NTOK - 1);
constexpr size_t WS_Q0    = WS_IDXI  + (size_t)BATCH * LEFT;          // [64,768]
constexpr size_t WS_XB    = WS_Q0  + (size_t)BATCH * CDIM;            // [MPAD,768] bf16
constexpr size_t WS_WB    = WS_XB  + (size_t)MPAD * CDIM / 2;         // [2304,768] bf16
constexpr size_t WS_PB    = WS_WB  + (size_t)3 * CDIM * CDIM / 2;     // [768,768] bf16
constexpr size_t WS_QB    = WS_PB  + (size_t)CDIM * CDIM / 2;         // [BH,197,64] bf16
constexpr size_t WS_KB    = WS_QB  + (size_t)BH * NTOK * HD / 2;      // [BH,197,64] bf16
constexpr size_t WS_VTB   = WS_KB  + (size_t)BH * NTOK * HD / 2;      // [BH,64,224] bf16
constexpr size_t WS_AOB   = WS_VTB + (size_t)BH * HD * KPAD / 2;      // [MPAD,768] bf16
constexpr size_t WS_U     = WS_AOB + (size_t)MPAD * CDIM / 2;         // [BH,768] fp32
constexpr size_t WS_S     = WS_U   + (size_t)BH * CDIM;               // [BH,208] fp32

typedef __attribute__((ext_vector_type(8))) short short8;
typedef __attribute__((ext_vector_type(4))) float floatx4;

__device__ __forceinline__ ushort f2bf(float x) {
    __hip_bfloat16 h = __float2bfloat16(x);
    return *(ushort*)&h;
}

// async global->LDS, 16B per lane; LDS dest must be wave-uniform base + lane*16
__device__ __forceinline__ void load_lds16(const ushort* g, ushort* l) {
    __builtin_amdgcn_global_load_lds(
        (const __attribute__((address_space(1))) uint32_t*)(uintptr_t)g,
        (__attribute__((address_space(3))) uint32_t*)(uint32_t)(uintptr_t)l,
        16, 0, 0);
}

// ---------------------------------------------------------------------------
// Fused fp32 -> bf16 cast of x (padded to MPAD rows), qkv_w, proj_w.
// ---------------------------------------------------------------------------
constexpr int X_N4  = MROWS * CDIM / 4;         // valid x float4s
constexpr int X_NP4 = MPAD * CDIM / 4;          // padded x float4s
constexpr int W_N4  = 3 * CDIM * CDIM / 4;
constexpr int P_N4  = CDIM * CDIM / 4;
constexpr int CAST_TOTAL = X_NP4 + W_N4 + P_N4; // multiple of 256

__global__ __launch_bounds__(256) void cast_all_kernel(const float* __restrict__ x,
                                                       const float* __restrict__ qkv_w,
                                                       const float* __restrict__ proj_w,
                                                       ushort* __restrict__ xb,
                                                       ushort* __restrict__ wb,
                                                       ushort* __restrict__ pb) {
    int i = blockIdx.x * 256 + threadIdx.x;
    const float* src;
    ushort* dst;
    int j, valid;
    if (i < X_NP4) {
        src = x; dst = xb; j = i; valid = (j < X_N4);
    } else if (i < X_NP4 + W_N4) {
        src = qkv_w; dst = wb; j = i - X_NP4; valid = 1;
    } else if (i < CAST_TOTAL) {
        src = proj_w; dst = pb; j = i - X_NP4 - W_N4; valid = 1;
    } else {
        return;
    }
    ushort4 h4 = make_ushort4(0, 0, 0, 0);
    if (valid) {
        float4 a = ((const float4*)src)[j];
        h4 = make_ushort4(f2bf(a.x), f2bf(a.y), f2bf(a.z), f2bf(a.w));
    }
    ((ushort4*)dst)[j] = h4;
}

// ---------------------------------------------------------------------------
// Exact fp32 q row-0 projection, wave-parallel over K:
// q0[b,c] = x[b,0,:] . qkv_w[c,:] + qkv_b[c].
// ---------------------------------------------------------------------------
__global__ __launch_bounds__(256) void q0_kernel(const float* __restrict__ x,
                                                 const float* __restrict__ qkv_w,
                                                 const float* __restrict__ qkv_b,
                                                 float* __restrict__ q0) {
    const int wv   = threadIdx.x >> 6;
    const int lane = threadIdx.x & 63;
    constexpr int CG = CDIM / 4;            // 192 c-groups of 4
    const int b = blockIdx.x / CG;
    const int c = (blockIdx.x - b * CG) * 4 + wv;

    const float* xr = x + (size_t)b * NTOK * CDIM;
    const float* wr = qkv_w + (size_t)c * CDIM;
    float s = 0.f;
#pragma unroll
    for (int i = 0; i < 3; i++) {
        float4 xv = *(const float4*)(xr + lane * 4 + i * 256);
        float4 wv4 = *(const float4*)(wr + lane * 4 + i * 256);
        s += xv.x * wv4.x + xv.y * wv4.y + xv.z * wv4.z + xv.w * wv4.w;
    }
#pragma unroll
    for (int off = 32; off >= 1; off >>= 1) s += __shfl_xor(s, off);
    if (lane == 0) q0[(size_t)b * CDIM + c] = s + qkv_b[c];
}

// ---------------------------------------------------------------------------
// u[bh, c] = sum_d q0[b, h*64+d] * Wk[h*64+d, c]   (Wk = qkv_w rows 768..1535)
// ---------------------------------------------------------------------------
__global__ __launch_bounds__(256) void u_kernel(const float* __restrict__ q0,
                                                const float* __restrict__ qkv_w,
                                                float* __restrict__ U) {
    const int bh = blockIdx.x;
    const int b  = bh / NH;
    const int h  = bh - b * NH;
    const int t  = threadIdx.x;

    __shared__ float q0s[HD];
    if (t < HD) q0s[t] = q0[(size_t)b * CDIM + h * HD + t];
    __syncthreads();

    const float* wk = qkv_w + (size_t)(CDIM + h * HD) * CDIM;
    float a0 = 0.f, a1 = 0.f, a2 = 0.f;
    for (int d = 0; d < HD; d++) {
        const float qd = q0s[d];
        const float* row = wk + (size_t)d * CDIM;
        a0 = fmaf(qd, row[t],       a0);
        a1 = fmaf(qd, row[t + 256], a1);
        a2 = fmaf(qd, row[t + 512], a2);
    }
    float* ub = U + (size_t)bh * CDIM;
    ub[t] = a0; ub[t + 256] = a1; ub[t + 512] = a2;
}

// ---------------------------------------------------------------------------
// S[bh, j] = u[bh,:] . x[b,j,:]   — 4 waves per block, one (j,b) per wave.
// ---------------------------------------------------------------------------
__global__ __launch_bounds__(256) void score_kernel(const float* __restrict__ x,
                                                    const float* __restrict__ U,
                                                    float* __restrict__ S) {
    const int wv   = threadIdx.x >> 6;
    const int lane = threadIdx.x & 63;
    const int j    = blockIdx.x * 4 + wv;
    const int b    = blockIdx.y;
    if (j >= NTOK) return;

    const float* xr = x + ((size_t)b * NTOK + j) * CDIM;
    float4 xv[3];
#pragma unroll
    for (int i = 0; i < 3; i++) xv[i] = *(const float4*)(xr + lane * 4 + i * 256);

    for (int h = 0; h < NH; h++) {
        const float* ur = U + (size_t)(b * NH + h) * CDIM;
        float s = 0.f;
#pragma unroll
        for (int i = 0; i < 3; i++) {
            float4 uv = *(const float4*)(ur + lane * 4 + i * 256);
            s += xv[i].x * uv.x + xv[i].y * uv.y + xv[i].z * uv.z + xv[i].w * uv.w;
        }
#pragma unroll
        for (int off = 32; off >= 1; off >>= 1) s += __shfl_xor(s, off);
        if (lane == 0) S[(size_t)(b * NH + h) * SPAD + j] = s;
    }
}

// ---------------------------------------------------------------------------
// 128x128 / BK=32 / 4-wave bf16 MFMA GEMM — the R4/R6-measured m97 geometry
// (93-95us QKV, at the m102 shape-curve expectation for this problem size).
// MODE 0: fp32 row-major O0f[Mvalid, N].
// MODE 1: qkv split (bf16): q -> O0q[bh][tok][64], k -> O1k[bh][tok][64],
//         v -> DENSE O2vd[m][768] (32B-segment stores; transposed later).
// ---------------------------------------------------------------------------
template <int MODE, int NCOLT>
__global__ __launch_bounds__(256, 4) void mfma_gemm128(
    const ushort* __restrict__ A, const ushort* __restrict__ W,
    const float* __restrict__ bias,
    float* __restrict__ O0f, ushort* __restrict__ O0q,
    ushort* __restrict__ O1k, ushort* __restrict__ O2vd,
    int Mvalid, int N) {
    constexpr int K   = CDIM;               // 768
    constexpr int BK  = 32;
    constexpr int NTK = K / BK;             // 24
    __shared__ ushort sA[2 * 128 * BK];     // 16 KiB
    __shared__ ushort sB[2 * 128 * BK];     // 16 KiB

    const int t    = threadIdx.x;
    const int lane = t & 63;
    const int w    = t >> 6;
    const int wm   = (w >> 1) * 64;         // M-half of tile
    const int wn   = (w & 1) * 64;          // N-half of tile
    const int fr   = lane & 15;
    const int fq   = lane >> 4;             // 0..3
    const int f3   = lane & 3;              // == fr & 3

    // bijective XCD-aware swizzle (m204): contiguous wgid chunk per XCD
    int row, col;
    {
        constexpr int nwg = NROWT * NCOLT;
        constexpr int q = nwg >> 3, r = nwg & 7;
        const int xcd = blockIdx.x & 7, lin = blockIdx.x >> 3;
        const int wg = (xcd < r ? xcd * (q + 1) : r * (q + 1) + (xcd - r) * q) + lin;
        row = wg / NCOLT; col = wg - row * NCOLT;
    }
    const int rowBase = row * 128;
    const int colBase = col * 128;

    // stage one 128x32 tile (8 KB): linear LDS dest, inverse-swizzled source
    auto stage = [&](const ushort* __restrict__ G, ushort* dst, int grow0, int kt) {
#pragma unroll
        for (int i = 0; i < 2; ++i) {
            const int l  = i * 256 + t;
            const int rl = l >> 2;                       // row (4 thr/row)
            const int sl = (l & 3) ^ (rl & 3);           // swizzled 16B slot
            load_lds16(G + (size_t)(grow0 + rl) * K + kt * BK + sl * 8,
                       dst + l * 8);
        }
    };

    floatx4 acc[4][4];
#pragma unroll
    for (int i = 0; i < 4; ++i)
#pragma unroll
        for (int j = 0; j < 4; ++j)
#pragma unroll
            for (int r2 = 0; r2 < 4; ++r2) acc[i][j][r2] = 0.f;

    // read-side swizzled slot offset (ushort units): logical slot fq
    const int s0 = (fq ^ f3) * 8;

    // prologue: tile 0 -> buffer 0
    stage(A, sA, rowBase, 0);
    stage(W, sB, colBase, 0);

    for (int kt = 0; kt < NTK; ++kt) {
        __syncthreads();                     // drains vm+lgkm: buf[cur] ready,
                                             // buf[cur^1] reads complete
        const int cb = (kt & 1) << 12;       // current buffer (ushort offset)
        if (kt + 1 < NTK) {                  // prefetch next tile
            stage(A, sA + (cb ^ 4096), rowBase, kt + 1);
            stage(W, sB + (cb ^ 4096), colBase, kt + 1);
        }

        const ushort* pa = sA + cb + (wm + fr) * BK;
        const ushort* pb = sB + cb + (wn + fr) * BK;
        short8 af[4], bf[4];
#pragma unroll
        for (int i = 0; i < 4; ++i) {
            af[i] = *(const short8*)(pa + i * 512 + s0);
            bf[i] = *(const short8*)(pb + i * 512 + s0);
        }
#pragma unroll
        for (int i = 0; i < 4; ++i)
#pragma unroll
            for (int j = 0; j < 4; ++j)
                acc[i][j] = __builtin_amdgcn_mfma_f32_16x16x32_bf16(
                    af[i], bf[j], acc[i][j], 0, 0, 0);
    }

    // epilogue: C/D layout col(n)=lane&15, row(m)=(lane>>4)*4+reg
#pragma unroll
    for (int j = 0; j < 4; ++j) {
        const int nn = colBase + wn + j * 16 + fr;
        const float bq = bias[nn];
        if (MODE == 0) {
#pragma unroll
            for (int i = 0; i < 4; ++i) {
                const int mb = rowBase + wm + i * 16 + fq * 4;
#pragma unroll
                for (int r2 = 0; r2 < 4; ++r2) {
                    const int mm = mb + r2;
                    if (mm < Mvalid) O0f[(size_t)mm * N + nn] = acc[i][j][r2] + bq;
                }
            }
        } else {
            const int which = nn / CDIM;     // wave-uniform per col-tile
            const int nc    = nn - which * CDIM;
            const int h     = nc >> 6;
            const int d     = nc & 63;
#pragma unroll
            for (int i = 0; i < 4; ++i) {
                const int mb = rowBase + wm + i * 16 + fq * 4;
#pragma unroll
                for (int r2 = 0; r2 < 4; ++r2) {
                    const int mm = mb + r2;
                    if (mm < Mvalid) {
                        const int b   = mm / NTOK;
                        const int tok = mm - b * NTOK;
                        const int bh  = b * NH + h;
                        const ushort val = f2bf(acc[i][j][r2] + bq);
                        if (which == 0)      O0q[((size_t)bh * NTOK + tok) * HD + d] = val;
                        else if (which == 1) O1k[((size_t)bh * NTOK + tok) * HD + d] = val;
                        else                 O2vd[(size_t)mm * CDIM + nc] = val;  // dense
                    }
                }
            }
        }
    }
}

// ---------------------------------------------------------------------------
// Vd[b*197+tok][768] (dense v, bf16) -> Vtb[bh][d][KPAD] via LDS transpose.
// Coalesced 128B row reads, 448B row writes; zero-fills pad cols 197..223.
// ---------------------------------------------------------------------------
__global__ __launch_bounds__(256) void v_transpose_kernel(const ushort* __restrict__ Vd,
                                                          ushort* __restrict__ Vtb) {
    const int bh = blockIdx.x;             // 0..767
    const int b  = bh / NH;
    const int h  = bh - b * NH;
    const int t  = threadIdx.x;

    __shared__ ushort tile[HD][KPAD + 9];  // odd pad stride vs bank conflicts

    const int d  = t & 63;
    const int tt = t >> 6;                 // 0..3
    const ushort* src = Vd + (size_t)b * NTOK * CDIM + h * HD + d;
    for (int tok0 = 0; tok0 < KPAD; tok0 += 4) {
        const int tok = tok0 + tt;
        ushort v = 0;
        if (tok < NTOK) v = src[(size_t)tok * CDIM];
        tile[d][tok] = v;
    }
    __syncthreads();

    uint* dst = (uint*)(Vtb + (size_t)bh * HD * KPAD);
    constexpr int C2 = KPAD / 2;           // 112 u32 per d-row
    for (int idx = t; idx < HD * C2; idx += 256) {
        const int dd = idx / C2;
        const int c  = idx - dd * C2;
        const uint lo = tile[dd][2 * c];
        const uint hi = tile[dd][2 * c + 1];
        dst[dd * C2 + c] = lo | (hi << 16);
    }
}

// ---------------------------------------------------------------------------
// MFMA flash attention, 4 q-tiles per wave: one wave (64 threads) per
// (q-tile-group, b*h).  K/V fragments are loaded ONCE per 32-key step and
// reused by 4 q-tiles (32 MFMA : 8 VMEM loads vs 8:8 before — the 1-wave
// structure was VMEM-latency-bound).  S^T = K.Q^T so queries sit in
// C-columns; online softmax per-lane + two shfl_xor quad-reduces; per-tile
// P staged in its own LDS buffer (one barrier per step).
// ---------------------------------------------------------------------------
constexpr int QTPW = 4;                 // q-tiles per wave
constexpr int NQG  = 4;                 // ceil(13 / QTPW) groups

__global__ __launch_bounds__(64) void attn_mfma_kernel(const ushort* __restrict__ Qb,
                                                       const ushort* __restrict__ Kb,
                                                       const ushort* __restrict__ Vtb,
                                                       ushort* __restrict__ AOb) {
    const int g  = blockIdx.x;          // 0..3 (q-tile group)
    const int bh = blockIdx.y;          // 0..767
    const int b  = bh / NH;
    const int h  = bh - b * NH;
    const int lane = threadIdx.x;
    const int qc   = lane & 15;
    const int quad = lane >> 4;
    const int ntv  = min(QTPW, 13 - g * QTPW);   // valid tiles (4,4,4,1)

    __shared__ ushort Pl[QTPW][16][32];
    __shared__ float  alf[QTPW][16], lf[QTPW][16];

    const ushort* Qh = Qb  + (size_t)bh * NTOK * HD;
    const ushort* Kh = Kb  + (size_t)bh * NTOK * HD;
    const ushort* Vh = Vtb + (size_t)bh * HD * KPAD;

    short8 qf[QTPW][2];
#pragma unroll
    for (int ti = 0; ti < QTPW; ++ti) {
        if (ti < ntv) {
            const int qrow = min((g * QTPW + ti) * 16 + qc, NTOK - 1);
            qf[ti][0] = *(const short8*)(Qh + (size_t)qrow * HD + quad * 8);
            qf[ti][1] = *(const short8*)(Qh + (size_t)qrow * HD + 32 + quad * 8);
        }
    }

    floatx4 o[QTPW][4];
#pragma unroll
    for (int ti = 0; ti < QTPW; ++ti)
#pragma unroll
        for (int s = 0; s < 4; ++s)
#pragma unroll
            for (int r = 0; r < 4; ++r) o[ti][s][r] = 0.f;
    float m[QTPW], l[QTPW];
#pragma unroll
    for (int ti = 0; ti < QTPW; ++ti) { m[ti] = -INFINITY; l[ti] = 0.f; }

    for (int c0 = 0; c0 < NTOK; c0 += 32) {
        const int kr0 = min(c0 + qc, NTOK - 1);
        const int kr1 = min(c0 + 16 + qc, NTOK - 1);
        const short8 kf00 = *(const short8*)(Kh + (size_t)kr0 * HD + quad * 8);
        const short8 kf01 = *(const short8*)(Kh + (size_t)kr0 * HD + 32 + quad * 8);
        const short8 kf10 = *(const short8*)(Kh + (size_t)kr1 * HD + quad * 8);
        const short8 kf11 = *(const short8*)(Kh + (size_t)kr1 * HD + 32 + quad * 8);

#pragma unroll
        for (int ti = 0; ti < QTPW; ++ti) {
            if (ti >= ntv) continue;        // wave-uniform guard
            floatx4 s0 = {0.f, 0.f, 0.f, 0.f}, s1 = {0.f, 0.f, 0.f, 0.f};
            s0 = __builtin_amdgcn_mfma_f32_16x16x32_bf16(kf00, qf[ti][0], s0, 0, 0, 0);
            s0 = __builtin_amdgcn_mfma_f32_16x16x32_bf16(kf01, qf[ti][1], s0, 0, 0, 0);
            s1 = __builtin_amdgcn_mfma_f32_16x16x32_bf16(kf10, qf[ti][0], s1, 0, 0, 0);
            s1 = __builtin_amdgcn_mfma_f32_16x16x32_bf16(kf11, qf[ti][1], s1, 0, 0, 0);

            float sv[8];
            float mloc = -INFINITY;
#pragma unroll
            for (int r = 0; r < 4; ++r) {
                const int key0 = c0 + quad * 4 + r;
                const int key1 = key0 + 16;
                sv[r]     = (key0 < NTOK) ? s0[r] * 0.125f : -1e30f;
                sv[4 + r] = (key1 < NTOK) ? s1[r] * 0.125f : -1e30f;
                mloc = fmaxf(mloc, fmaxf(sv[r], sv[4 + r]));
            }
            mloc = fmaxf(mloc, __shfl_xor(mloc, 16));
            mloc = fmaxf(mloc, __shfl_xor(mloc, 32));
            const float mnew  = fmaxf(m[ti], mloc);
            const float alpha = __expf(m[ti] - mnew);
            float p[8], ps = 0.f;
#pragma unroll
            for (int i = 0; i < 8; ++i) { p[i] = __expf(sv[i] - mnew); ps += p[i]; }
            ps += __shfl_xor(ps, 16);
            ps += __shfl_xor(ps, 32);
            l[ti] = l[ti] * alpha + ps;
            m[ti] = mnew;

#pragma unroll
            for (int r = 0; r < 4; ++r) {
                Pl[ti][qc][quad * 4 + r]      = f2bf(p[r]);
                Pl[ti][qc][16 + quad * 4 + r] = f2bf(p[4 + r]);
            }
            if (quad == 0) alf[ti][qc] = alpha;
        }
        __syncthreads();

        short8 pf[QTPW];
#pragma unroll
        for (int ti = 0; ti < QTPW; ++ti) {
            if (ti >= ntv) continue;
            pf[ti] = *(const short8*)&Pl[ti][qc][quad * 8];
            float ar[4];
#pragma unroll
            for (int r = 0; r < 4; ++r) ar[r] = alf[ti][quad * 4 + r];
#pragma unroll
            for (int s = 0; s < 4; ++s)
#pragma unroll
                for (int r = 0; r < 4; ++r) o[ti][s][r] *= ar[r];
        }

#pragma unroll
        for (int s = 0; s < 4; ++s) {
            const short8 vf = *(const short8*)(Vh + (size_t)(s * 16 + qc) * KPAD + c0 + quad * 8);
#pragma unroll
            for (int ti = 0; ti < QTPW; ++ti)
                if (ti < ntv)
                    o[ti][s] = __builtin_amdgcn_mfma_f32_16x16x32_bf16(
                        pf[ti], vf, o[ti][s], 0, 0, 0);
        }
        __syncthreads();                    // Pl reused next step
    }

#pragma unroll
    for (int ti = 0; ti < QTPW; ++ti)
        if (ti < ntv && quad == 0) lf[ti][qc] = l[ti];
    __syncthreads();

#pragma unroll
    for (int ti = 0; ti < QTPW; ++ti) {
        if (ti >= ntv) continue;
        const int qt = g * QTPW + ti;
#pragma unroll
        for (int r = 0; r < 4; ++r) {
            const int tok = qt * 16 + quad * 4 + r;
            if (tok >= NTOK) continue;
            const float inv = 1.f / lf[ti][quad * 4 + r];
            ushort* dst = AOb + ((size_t)(b * NTOK + tok)) * CDIM + h * HD;
#pragma unroll
            for (int s = 0; s < 4; ++s) dst[s * 16 + qc] = f2bf(o[ti][s][r] * inv);
        }
    }
}

// ---------------------------------------------------------------------------
// Fused cls softmax (per head, exact fp32) + head-average + exact top-137
// (stable descending) + cls output. One block per batch.
// ---------------------------------------------------------------------------
__global__ __launch_bounds__(256) void topk_fused_kernel(const float* __restrict__ S,
                                                         const float* __restrict__ q0,
                                                         const float* __restrict__ qkv_b,
                                                         int* __restrict__ idxI,
                                                         float* __restrict__ idxOut,
                                                         float* __restrict__ outCls) {
    const int b    = blockIdx.x;
    const int t    = threadIdx.x;
    const int lane = t & 63;
    const int w    = t >> 6;

    __shared__ float qbv[NH];
    __shared__ float redm[4], reds[4];
    __shared__ float vsh[NTOK - 1];

    if (w == 0) {
        for (int h = 0; h < NH; ++h) {
            float p = q0[(size_t)b * CDIM + h * HD + lane] * qkv_b[CDIM + h * HD + lane];
#pragma unroll
            for (int off = 32; off >= 1; off >>= 1) p += __shfl_xor(p, off);
            if (lane == 0) qbv[h] = p;
        }
    }
    __syncthreads();

    float macc = 0.f;
    for (int h = 0; h < NH; ++h) {
        const float qb = qbv[h];
        const float sv = (t < NTOK) ? (S[(size_t)(b * NH + h) * SPAD + t] + qb) * 0.125f
                                    : -INFINITY;
        float mloc = sv;
#pragma unroll
        for (int off = 32; off >= 1; off >>= 1) mloc = fmaxf(mloc, __shfl_xor(mloc, off));
        if (lane == 0) redm[w] = mloc;
        __syncthreads();
        const float mx = fmaxf(fmaxf(redm[0], redm[1]), fmaxf(redm[2], redm[3]));
        const float p = (t < NTOK) ? expf(sv - mx) : 0.f;
        float ls = p;
#pragma unroll
        for (int off = 32; off >= 1; off >>= 1) ls += __shfl_xor(ls, off);
        if (lane == 0) reds[w] = ls;
        __syncthreads();
        const float denom = (reds[0] + reds[1]) + (reds[2] + reds[3]);
        macc += p / denom;
        __syncthreads();                  // protect redm/reds for next h
    }

    if (t >= 1 && t < NTOK) {
        const float val = macc * (1.f / 12.f);
        vsh[t - 1] = val;
        outCls[(size_t)b * (NTOK - 1) + (t - 1)] = val;
    }
    __syncthreads();

    if (t < NTOK - 1) {
        const float vi = vsh[t];
        int rank = 0;
        for (int j = 0; j < NTOK - 1; j++) {
            const float vj = vsh[j];
            rank += (vj > vi) || (vj == vi && j < t);
        }
        if (rank < LEFT) {
            idxI[b * LEFT + rank]   = t;
            idxOut[b * LEFT + rank] = (float)t;
        }
    }
}

// index = broadcast idx over channel dim, float4-vectorized (CDIM%4==0)
__global__ void fill_index_kernel(const int* __restrict__ idxI,
                                  float* __restrict__ dst) {
    int tid = blockIdx.x * 256 + threadIdx.x;
    constexpr int C4 = CDIM / 4;
    if (tid >= BATCH * LEFT * C4) return;
    float v = (float)idxI[tid / C4];
    ((float4*)dst)[tid] = make_float4(v, v, v, v);
}

extern "C" void kernel_launch(void* const* d_in, const int* in_sizes, int n_in,
                              void* d_out, int out_size, void* d_ws, size_t ws_size,
                              hipStream_t stream) {
    const float* x      = (const float*)d_in[0];
    const float* qkv_w  = (const float*)d_in[1];  // [2304,768]
    const float* qkv_b  = (const float*)d_in[2];  // [2304]
    const float* proj_w = (const float*)d_in[3];  // [768,768]
    const float* proj_b = (const float*)d_in[4];  // [768]
    float* out = (float*)d_out;

    float*  ws    = (float*)d_ws;
    int*    idxi  = (int*)(ws + WS_IDXI);
    float*  q0    = ws + WS_Q0;
    ushort* xb    = (ushort*)(ws + WS_XB);
    ushort* wb    = (ushort*)(ws + WS_WB);
    ushort* pb    = (ushort*)(ws + WS_PB);
    ushort* qb    = (ushort*)(ws + WS_QB);
    ushort* kb    = (ushort*)(ws + WS_KB);
    ushort* vtb   = (ushort*)(ws + WS_VTB);
    ushort* aob   = (ushort*)(ws + WS_AOB);
    ushort* vd    = aob;   // dense-v staging aliases aob (free until attn runs)
    float*  U     = ws + WS_U;
    float*  S     = ws + WS_S;

    // 1) fused fp32 -> bf16 casts (x padded to MPAD, qkv_w, proj_w)
    cast_all_kernel<<<CAST_TOTAL / 256, 256, 0, stream>>>(x, qkv_w, proj_w, xb, wb, pb);

    // 2) Exact fp32 cls-score side path (top-k precision domain)
    q0_kernel<<<BATCH * (CDIM / 4), 256, 0, stream>>>(x, qkv_w, qkv_b, q0);
    u_kernel<<<BH, 256, 0, stream>>>(q0, qkv_w, U);
    score_kernel<<<dim3((NTOK + 3) / 4, BATCH), 256, 0, stream>>>(x, U, S);

    // 3) QKV projection (128²/BK32 MFMA, 4 blocks/CU) + q/k split, v dense
    mfma_gemm128<1, 18><<<NROWT * 18, 256, 0, stream>>>(
        xb, wb, qkv_b, nullptr, qb, kb, vd, MROWS, 3 * CDIM);

    // 3b) dense v -> transposed vtb (coalesced; zero-fills pad cols)
    v_transpose_kernel<<<BH, 256, 0, stream>>>(vd, vtb);

    // 4) MFMA flash attention (4 q-tiles/wave) -> bf16 pre-proj out
    attn_mfma_kernel<<<dim3(NQG, BH), 64, 0, stream>>>(qb, kb, vtb, aob);

    // 5) Output projection (128²/BK32 MFMA) -> fp32 out
    mfma_gemm128<0, 6><<<NROWT * 6, 256, 0, stream>>>(
        aob, pb, proj_b, out + OUT_OFF_OUT, nullptr, nullptr, nullptr,
        MROWS, CDIM);

    // 6) Fused cls softmax + head-average + exact top-137 + cls output
    topk_fused_kernel<<<BATCH, 256, 0, stream>>>(S, q0, qkv_b, idxi,
                                                 out + OUT_OFF_IDX,
                                                 out + OUT_OFF_CLS);

    // 7) Broadcast indices over channels (float4)
    fill_index_kernel<<<((size_t)BATCH * LEFT * (CDIM / 4) + 255) / 256, 256, 0, stream>>>(
        idxi, out + OUT_OFF_INDEX);
}

// Round 8
// 326.918 us; speedup vs baseline: 1.4442x; 1.1019x over previous
//
#include <hip/hip_runtime.h>
#include <hip/hip_bf16.h>
#include <stdint.h>

// Problem constants
constexpr int BATCH = 64;
constexpr int NTOK  = 197;
constexpr int CDIM  = 768;
constexpr int NH    = 12;
constexpr int HD    = 64;
constexpr int MROWS = BATCH * NTOK;        // 12608
constexpr int MPAD  = 12800;               // 100 * 128 (GEMM row tiles)
constexpr int NROWT = MPAD / 128;          // 100
constexpr int LEFT  = 137;                 // int(0.7 * 196)
constexpr int KPAD  = 224;                 // keys padded (7 * 32)
constexpr int BH    = BATCH * NH;          // 768
constexpr int SPAD  = 208;                 // score row stride

// Output layout (flat float32, concatenated in return order)
constexpr size_t OUT_OFF_OUT   = 0;                                   // [64,197,768]
constexpr size_t OUT_OFF_INDEX = (size_t)BATCH * NTOK * CDIM;         // [64,137,768]
constexpr size_t OUT_OFF_IDX   = OUT_OFF_INDEX + (size_t)BATCH * LEFT * CDIM; // [64,137]
constexpr size_t OUT_OFF_CLS   = OUT_OFF_IDX + (size_t)BATCH * LEFT;  // [64,196]

// Workspace layout (float units; bf16 regions counted as elems/2)
constexpr size_t WS_CLSPH = 0;                                        // (unused, kept for layout)
constexpr size_t WS_CLSF  = WS_CLSPH + (size_t)BH * (NTOK - 1);
constexpr size_t WS_IDXI  = WS_CLSF  + (size_t)BATCH * (NTOK - 1);
constexpr size_t WS_Q0    = WS_IDXI  + (size_t)BATCH * LEFT;          // qbW[BH] (reused region)
constexpr size_t WS_XB    = WS_Q0  + (size_t)BATCH * CDIM;            // [MPAD,768] bf16
constexpr size_t WS_WB    = WS_XB  + (size_t)MPAD * CDIM / 2;         // [2304,768] bf16
constexpr size_t WS_PB    = WS_WB  + (size_t)3 * CDIM * CDIM / 2;     // [768,768] bf16
constexpr size_t WS_QB    = WS_PB  + (size_t)CDIM * CDIM / 2;         // [BH,197,64] bf16
constexpr size_t WS_KB    = WS_QB  + (size_t)BH * NTOK * HD / 2;      // [BH,197,64] bf16
constexpr size_t WS_VTB   = WS_KB  + (size_t)BH * NTOK * HD / 2;      // dense v [MROWS,768] bf16 (region fits)
constexpr size_t WS_AOB   = WS_VTB + (size_t)BH * HD * KPAD / 2;      // [MPAD,768] bf16
constexpr size_t WS_U     = WS_AOB + (size_t)MPAD * CDIM / 2;         // [BH,768] fp32
constexpr size_t WS_S     = WS_U   + (size_t)BH * CDIM;               // [BH,208] fp32

typedef __attribute__((ext_vector_type(8))) short short8;
typedef __attribute__((ext_vector_type(4))) float floatx4;

__device__ __forceinline__ ushort f2bf(float x) {
    __hip_bfloat16 h = __float2bfloat16(x);
    return *(ushort*)&h;
}

// async global->LDS, 16B per lane; LDS dest must be wave-uniform base + lane*16
__device__ __forceinline__ void load_lds16(const ushort* g, ushort* l) {
    __builtin_amdgcn_global_load_lds(
        (const __attribute__((address_space(1))) uint32_t*)(uintptr_t)g,
        (__attribute__((address_space(3))) uint32_t*)(uint32_t)(uintptr_t)l,
        16, 0, 0);
}

// ---------------------------------------------------------------------------
// Fused fp32 -> bf16 cast of x (padded to MPAD rows), qkv_w, proj_w.
// ---------------------------------------------------------------------------
constexpr int X_N4  = MROWS * CDIM / 4;         // valid x float4s
constexpr int X_NP4 = MPAD * CDIM / 4;          // padded x float4s
constexpr int W_N4  = 3 * CDIM * CDIM / 4;
constexpr int P_N4  = CDIM * CDIM / 4;
constexpr int CAST_TOTAL = X_NP4 + W_N4 + P_N4; // multiple of 256

__global__ __launch_bounds__(256) void cast_all_kernel(const float* __restrict__ x,
                                                       const float* __restrict__ qkv_w,
                                                       const float* __restrict__ proj_w,
                                                       ushort* __restrict__ xb,
                                                       ushort* __restrict__ wb,
                                                       ushort* __restrict__ pb) {
    int i = blockIdx.x * 256 + threadIdx.x;
    const float* src;
    ushort* dst;
    int j, valid;
    if (i < X_NP4) {
        src = x; dst = xb; j = i; valid = (j < X_N4);
    } else if (i < X_NP4 + W_N4) {
        src = qkv_w; dst = wb; j = i - X_NP4; valid = 1;
    } else if (i < CAST_TOTAL) {
        src = proj_w; dst = pb; j = i - X_NP4 - W_N4; valid = 1;
    } else {
        return;
    }
    ushort4 h4 = make_ushort4(0, 0, 0, 0);
    if (valid) {
        float4 a = ((const float4*)src)[j];
        h4 = make_ushort4(f2bf(a.x), f2bf(a.y), f2bf(a.z), f2bf(a.w));
    }
    ((ushort4*)dst)[j] = h4;
}

// ---------------------------------------------------------------------------
// Fused exact fp32 side-path head kernel: one block per (b,h).
// Phase A: q0 slice (64 c's, wave-parallel over K, bitwise-identical reduction
//          order to the previous q0_kernel) into LDS.
// Phase B: qb[bh] = q0slice . k-bias slice (same shfl order as old topk).
// Phase C: U[bh,:] = q0slice @ Wk   (identical loop to previous u_kernel).
// Removes the separate q0 dispatch and the q0 global roundtrip.
// ---------------------------------------------------------------------------
__global__ __launch_bounds__(256) void u_kernel(const float* __restrict__ x,
                                                const float* __restrict__ qkv_w,
                                                const float* __restrict__ qkv_b,
                                                float* __restrict__ U,
                                                float* __restrict__ qbW) {
    const int bh = blockIdx.x;
    const int b  = bh / NH;
    const int h  = bh - b * NH;
    const int t  = threadIdx.x;
    const int wv   = t >> 6;
    const int lane = t & 63;

    __shared__ float x0s[CDIM];
    __shared__ float q0s[HD];

    if (t < 192) ((float4*)x0s)[t] = ((const float4*)(x + (size_t)b * NTOK * CDIM))[t];
    __syncthreads();

    // Phase A: 16 c's per wave
    for (int i = 0; i < 16; ++i) {
        const int cl = wv * 16 + i;            // 0..63
        const int c  = h * HD + cl;
        const float* wr = qkv_w + (size_t)c * CDIM;
        float s = 0.f;
#pragma unroll
        for (int k = 0; k < 3; ++k) {
            float4 xv  = *(const float4*)(x0s + lane * 4 + k * 256);
            float4 wv4 = *(const float4*)(wr  + lane * 4 + k * 256);
            s += xv.x * wv4.x + xv.y * wv4.y + xv.z * wv4.z + xv.w * wv4.w;
        }
#pragma unroll
        for (int off = 32; off >= 1; off >>= 1) s += __shfl_xor(s, off);
        if (lane == 0) q0s[cl] = s + qkv_b[c];
    }
    __syncthreads();

    // Phase B: qb scalar (wave 0), same order as the old topk qb reduce
    if (wv == 0) {
        float p = q0s[lane] * qkv_b[CDIM + h * HD + lane];
#pragma unroll
        for (int off = 32; off >= 1; off >>= 1) p += __shfl_xor(p, off);
        if (lane == 0) qbW[bh] = p;
    }

    // Phase C: U row (identical to previous u_kernel body)
    const float* wk = qkv_w + (size_t)(CDIM + h * HD) * CDIM;
    float a0 = 0.f, a1 = 0.f, a2 = 0.f;
    for (int d = 0; d < HD; d++) {
        const float qd = q0s[d];
        const float* row = wk + (size_t)d * CDIM;
        a0 = fmaf(qd, row[t],       a0);
        a1 = fmaf(qd, row[t + 256], a1);
        a2 = fmaf(qd, row[t + 512], a2);
    }
    float* ub = U + (size_t)bh * CDIM;
    ub[t] = a0; ub[t + 256] = a1; ub[t + 512] = a2;
}

// ---------------------------------------------------------------------------
// S[bh, j] = u[bh,:] . x[b,j,:]   — 4 waves per block, one (j,b) per wave.
// ---------------------------------------------------------------------------
__global__ __launch_bounds__(256) void score_kernel(const float* __restrict__ x,
                                                    const float* __restrict__ U,
                                                    float* __restrict__ S) {
    const int wv   = threadIdx.x >> 6;
    const int lane = threadIdx.x & 63;
    const int j    = blockIdx.x * 4 + wv;
    const int b    = blockIdx.y;
    if (j >= NTOK) return;

    const float* xr = x + ((size_t)b * NTOK + j) * CDIM;
    float4 xv[3];
#pragma unroll
    for (int i = 0; i < 3; i++) xv[i] = *(const float4*)(xr + lane * 4 + i * 256);

    for (int h = 0; h < NH; h++) {
        const float* ur = U + (size_t)(b * NH + h) * CDIM;
        float s = 0.f;
#pragma unroll
        for (int i = 0; i < 3; i++) {
            float4 uv = *(const float4*)(ur + lane * 4 + i * 256);
            s += xv[i].x * uv.x + xv[i].y * uv.y + xv[i].z * uv.z + xv[i].w * uv.w;
        }
#pragma unroll
        for (int off = 32; off >= 1; off >>= 1) s += __shfl_xor(s, off);
        if (lane == 0) S[(size_t)(b * NH + h) * SPAD + j] = s;
    }
}

// ---------------------------------------------------------------------------
// 128x128 / BK=32 / 4-wave bf16 MFMA GEMM — the R4/R6-measured m97 geometry
// (93-96us QKV, at the m102 shape-curve expectation for this problem size).
// MODE 0: fp32 row-major O0f[Mvalid, N].
// MODE 1: qkv split (bf16): q -> O0q[bh][tok][64], k -> O1k[bh][tok][64],
//         v -> DENSE O2vd[m][768] (attn transposes it in LDS itself).
// ---------------------------------------------------------------------------
template <int MODE, int NCOLT>
__global__ __launch_bounds__(256, 4) void mfma_gemm128(
    const ushort* __restrict__ A, const ushort* __restrict__ W,
    const float* __restrict__ bias,
    float* __restrict__ O0f, ushort* __restrict__ O0q,
    ushort* __restrict__ O1k, ushort* __restrict__ O2vd,
    int Mvalid, int N) {
    constexpr int K   = CDIM;               // 768
    constexpr int BK  = 32;
    constexpr int NTK = K / BK;             // 24
    __shared__ ushort sA[2 * 128 * BK];     // 16 KiB
    __shared__ ushort sB[2 * 128 * BK];     // 16 KiB

    const int t    = threadIdx.x;
    const int lane = t & 63;
    const int w    = t >> 6;
    const int wm   = (w >> 1) * 64;         // M-half of tile
    const int wn   = (w & 1) * 64;          // N-half of tile
    const int fr   = lane & 15;
    const int fq   = lane >> 4;             // 0..3
    const int f3   = lane & 3;              // == fr & 3

    // bijective XCD-aware swizzle (m204): contiguous wgid chunk per XCD
    int row, col;
    {
        constexpr int nwg = NROWT * NCOLT;
        constexpr int q = nwg >> 3, r = nwg & 7;
        const int xcd = blockIdx.x & 7, lin = blockIdx.x >> 3;
        const int wg = (xcd < r ? xcd * (q + 1) : r * (q + 1) + (xcd - r) * q) + lin;
        row = wg / NCOLT; col = wg - row * NCOLT;
    }
    const int rowBase = row * 128;
    const int colBase = col * 128;

    // stage one 128x32 tile (8 KB): linear LDS dest, inverse-swizzled source
    auto stage = [&](const ushort* __restrict__ G, ushort* dst, int grow0, int kt) {
#pragma unroll
        for (int i = 0; i < 2; ++i) {
            const int l  = i * 256 + t;
            const int rl = l >> 2;                       // row (4 thr/row)
            const int sl = (l & 3) ^ (rl & 3);           // swizzled 16B slot
            load_lds16(G + (size_t)(grow0 + rl) * K + kt * BK + sl * 8,
                       dst + l * 8);
        }
    };

    floatx4 acc[4][4];
#pragma unroll
    for (int i = 0; i < 4; ++i)
#pragma unroll
        for (int j = 0; j < 4; ++j)
#pragma unroll
            for (int r2 = 0; r2 < 4; ++r2) acc[i][j][r2] = 0.f;

    // read-side swizzled slot offset (ushort units): logical slot fq
    const int s0 = (fq ^ f3) * 8;

    // prologue: tile 0 -> buffer 0
    stage(A, sA, rowBase, 0);
    stage(W, sB, colBase, 0);

    for (int kt = 0; kt < NTK; ++kt) {
        __syncthreads();                     // drains vm+lgkm: buf[cur] ready,
                                             // buf[cur^1] reads complete
        const int cb = (kt & 1) << 12;       // current buffer (ushort offset)
        if (kt + 1 < NTK) {                  // prefetch next tile
            stage(A, sA + (cb ^ 4096), rowBase, kt + 1);
            stage(W, sB + (cb ^ 4096), colBase, kt + 1);
        }

        const ushort* pa = sA + cb + (wm + fr) * BK;
        const ushort* pb = sB + cb + (wn + fr) * BK;
        short8 af[4], bf[4];
#pragma unroll
        for (int i = 0; i < 4; ++i) {
            af[i] = *(const short8*)(pa + i * 512 + s0);
            bf[i] = *(const short8*)(pb + i * 512 + s0);
        }
#pragma unroll
        for (int i = 0; i < 4; ++i)
#pragma unroll
            for (int j = 0; j < 4; ++j)
                acc[i][j] = __builtin_amdgcn_mfma_f32_16x16x32_bf16(
                    af[i], bf[j], acc[i][j], 0, 0, 0);
    }

    // epilogue: C/D layout col(n)=lane&15, row(m)=(lane>>4)*4+reg
#pragma unroll
    for (int j = 0; j < 4; ++j) {
        const int nn = colBase + wn + j * 16 + fr;
        const float bq = bias[nn];
        if (MODE == 0) {
#pragma unroll
            for (int i = 0; i < 4; ++i) {
                const int mb = rowBase + wm + i * 16 + fq * 4;
#pragma unroll
                for (int r2 = 0; r2 < 4; ++r2) {
                    const int mm = mb + r2;
                    if (mm < Mvalid) O0f[(size_t)mm * N + nn] = acc[i][j][r2] + bq;
                }
            }
        } else {
            const int which = nn / CDIM;     // wave-uniform per col-tile
            const int nc    = nn - which * CDIM;
            const int h     = nc >> 6;
            const int d     = nc & 63;
#pragma unroll
            for (int i = 0; i < 4; ++i) {
                const int mb = rowBase + wm + i * 16 + fq * 4;
#pragma unroll
                for (int r2 = 0; r2 < 4; ++r2) {
                    const int mm = mb + r2;
                    if (mm < Mvalid) {
                        const int b   = mm / NTOK;
                        const int tok = mm - b * NTOK;
                        const int bh  = b * NH + h;
                        const ushort val = f2bf(acc[i][j][r2] + bq);
                        if (which == 0)      O0q[((size_t)bh * NTOK + tok) * HD + d] = val;
                        else if (which == 1) O1k[((size_t)bh * NTOK + tok) * HD + d] = val;
                        else                 O2vd[(size_t)mm * CDIM + nc] = val;  // dense
                    }
                }
            }
        }
    }
}

// ---------------------------------------------------------------------------
// MFMA flash attention, one block per (b,h): 4 waves share an LDS-transposed
// V tile (staged from the GEMM's dense v output — no separate transpose
// kernel / vtb roundtrip).  Wave wv owns q-tile groups {0-3},{4-6},{7-9},
// {10-12}.  K frags loaded once per 32-key step per wave and reused across
// its tiles.  S^T = K.Q^T; online softmax per-lane + two shfl_xor
// quad-reduces; per-(wave,tile) P staged in LDS.
// ---------------------------------------------------------------------------
__global__ __launch_bounds__(256) void attn_mfma_kernel(const ushort* __restrict__ Qb,
                                                        const ushort* __restrict__ Kb,
                                                        const ushort* __restrict__ Vd,
                                                        ushort* __restrict__ AOb) {
    const int bh = blockIdx.x;          // 0..767
    const int b  = bh / NH;
    const int h  = bh - b * NH;
    const int t  = threadIdx.x;
    const int wv   = t >> 6;
    const int lane = t & 63;
    const int qc   = lane & 15;
    const int quad = lane >> 4;

    constexpr int VSTR = KPAD + 8;      // 232 ushorts (464B rows, 16B-aligned)
    __shared__ ushort Vt[HD][VSTR];     // 29.7 KiB
    __shared__ ushort Pl[4][4][16][32]; // 16 KiB (per wave x per tile)
    __shared__ float  alf[4][4][16], lf[4][4][16];

    // stage V transposed from dense [tok][768] layout (coalesced 128B reads)
    {
        const int d  = t & 63;
        const int tt = t >> 6;
        const ushort* src = Vd + (size_t)b * NTOK * CDIM + h * HD + d;
        for (int tok0 = 0; tok0 < KPAD; tok0 += 4) {
            const int tok = tok0 + tt;
            ushort v = 0;
            if (tok < NTOK) v = src[(size_t)tok * CDIM];
            Vt[d][tok] = v;
        }
    }

    const ushort* Qh = Qb + (size_t)bh * NTOK * HD;
    const ushort* Kh = Kb + (size_t)bh * NTOK * HD;

    const int tile0 = (wv == 0) ? 0 : 4 + (wv - 1) * 3;   // 0,4,7,10
    const int ntv   = (wv == 0) ? 4 : 3;

    short8 qf[4][2];
#pragma unroll
    for (int ti = 0; ti < 4; ++ti) {
        if (ti < ntv) {
            const int qrow = min((tile0 + ti) * 16 + qc, NTOK - 1);
            qf[ti][0] = *(const short8*)(Qh + (size_t)qrow * HD + quad * 8);
            qf[ti][1] = *(const short8*)(Qh + (size_t)qrow * HD + 32 + quad * 8);
        }
    }

    floatx4 o[4][4];
#pragma unroll
    for (int ti = 0; ti < 4; ++ti)
#pragma unroll
        for (int s = 0; s < 4; ++s)
#pragma unroll
            for (int r = 0; r < 4; ++r) o[ti][s][r] = 0.f;
    float m[4], l[4];
#pragma unroll
    for (int ti = 0; ti < 4; ++ti) { m[ti] = -INFINITY; l[ti] = 0.f; }

    __syncthreads();                    // Vt ready

    for (int c0 = 0; c0 < NTOK; c0 += 32) {
        const int kr0 = min(c0 + qc, NTOK - 1);
        const int kr1 = min(c0 + 16 + qc, NTOK - 1);
        const short8 kf00 = *(const short8*)(Kh + (size_t)kr0 * HD + quad * 8);
        const short8 kf01 = *(const short8*)(Kh + (size_t)kr0 * HD + 32 + quad * 8);
        const short8 kf10 = *(const short8*)(Kh + (size_t)kr1 * HD + quad * 8);
        const short8 kf11 = *(const short8*)(Kh + (size_t)kr1 * HD + 32 + quad * 8);

#pragma unroll
        for (int ti = 0; ti < 4; ++ti) {
            if (ti >= ntv) continue;    // wave-uniform guard
            floatx4 s0 = {0.f, 0.f, 0.f, 0.f}, s1 = {0.f, 0.f, 0.f, 0.f};
            s0 = __builtin_amdgcn_mfma_f32_16x16x32_bf16(kf00, qf[ti][0], s0, 0, 0, 0);
            s0 = __builtin_amdgcn_mfma_f32_16x16x32_bf16(kf01, qf[ti][1], s0, 0, 0, 0);
            s1 = __builtin_amdgcn_mfma_f32_16x16x32_bf16(kf10, qf[ti][0], s1, 0, 0, 0);
            s1 = __builtin_amdgcn_mfma_f32_16x16x32_bf16(kf11, qf[ti][1], s1, 0, 0, 0);

            float sv[8];
            float mloc = -INFINITY;
#pragma unroll
            for (int r = 0; r < 4; ++r) {
                const int key0 = c0 + quad * 4 + r;
                const int key1 = key0 + 16;
                sv[r]     = (key0 < NTOK) ? s0[r] * 0.125f : -1e30f;
                sv[4 + r] = (key1 < NTOK) ? s1[r] * 0.125f : -1e30f;
                mloc = fmaxf(mloc, fmaxf(sv[r], sv[4 + r]));
            }
            mloc = fmaxf(mloc, __shfl_xor(mloc, 16));
            mloc = fmaxf(mloc, __shfl_xor(mloc, 32));
            const float mnew  = fmaxf(m[ti], mloc);
            const float alpha = __expf(m[ti] - mnew);
            float p[8], ps = 0.f;
#pragma unroll
            for (int i = 0; i < 8; ++i) { p[i] = __expf(sv[i] - mnew); ps += p[i]; }
            ps += __shfl_xor(ps, 16);
            ps += __shfl_xor(ps, 32);
            l[ti] = l[ti] * alpha + ps;
            m[ti] = mnew;

#pragma unroll
            for (int r = 0; r < 4; ++r) {
                Pl[wv][ti][qc][quad * 4 + r]      = f2bf(p[r]);
                Pl[wv][ti][qc][16 + quad * 4 + r] = f2bf(p[4 + r]);
            }
            if (quad == 0) alf[wv][ti][qc] = alpha;
        }
        __syncthreads();

        short8 pf[4];
#pragma unroll
        for (int ti = 0; ti < 4; ++ti) {
            if (ti >= ntv) continue;
            pf[ti] = *(const short8*)&Pl[wv][ti][qc][quad * 8];
            float ar[4];
#pragma unroll
            for (int r = 0; r < 4; ++r) ar[r] = alf[wv][ti][quad * 4 + r];
#pragma unroll
            for (int s = 0; s < 4; ++s)
#pragma unroll
                for (int r = 0; r < 4; ++r) o[ti][s][r] *= ar[r];
        }

#pragma unroll
        for (int s = 0; s < 4; ++s) {
            const short8 vf = *(const short8*)&Vt[s * 16 + qc][c0 + quad * 8];
#pragma unroll
            for (int ti = 0; ti < 4; ++ti)
                if (ti < ntv)
                    o[ti][s] = __builtin_amdgcn_mfma_f32_16x16x32_bf16(
                        pf[ti], vf, o[ti][s], 0, 0, 0);
        }
        __syncthreads();                // Pl reused next step
    }

#pragma unroll
    for (int ti = 0; ti < 4; ++ti)
        if (ti < ntv && quad == 0) lf[wv][ti][qc] = l[ti];
    __syncthreads();

#pragma unroll
    for (int ti = 0; ti < 4; ++ti) {
        if (ti >= ntv) continue;
        const int qt = tile0 + ti;
#pragma unroll
        for (int r = 0; r < 4; ++r) {
            const int tok = qt * 16 + quad * 4 + r;
            if (tok >= NTOK) continue;
            const float inv = 1.f / lf[wv][ti][quad * 4 + r];
            ushort* dst = AOb + ((size_t)(b * NTOK + tok)) * CDIM + h * HD;
#pragma unroll
            for (int s = 0; s < 4; ++s) dst[s * 16 + qc] = f2bf(o[ti][s][r] * inv);
        }
    }
}

// ---------------------------------------------------------------------------
// Fused cls softmax (per head, exact fp32) + head-average + exact top-137
// (stable descending) + cls output. One block per batch.
// ---------------------------------------------------------------------------
__global__ __launch_bounds__(256) void topk_fused_kernel(const float* __restrict__ S,
                                                         const float* __restrict__ qbW,
                                                         int* __restrict__ idxI,
                                                         float* __restrict__ idxOut,
                                                         float* __restrict__ outCls) {
    const int b    = blockIdx.x;
    const int t    = threadIdx.x;
    const int lane = t & 63;
    const int w    = t >> 6;

    __shared__ float qbv[NH];
    __shared__ float redm[4], reds[4];
    __shared__ float vsh[NTOK - 1];

    if (t < NH) qbv[t] = qbW[b * NH + t];
    __syncthreads();

    float macc = 0.f;
    for (int h = 0; h < NH; ++h) {
        const float qb = qbv[h];
        const float sv = (t < NTOK) ? (S[(size_t)(b * NH + h) * SPAD + t] + qb) * 0.125f
                                    : -INFINITY;
        float mloc = sv;
#pragma unroll
        for (int off = 32; off >= 1; off >>= 1) mloc = fmaxf(mloc, __shfl_xor(mloc, off));
        if (lane == 0) redm[w] = mloc;
        __syncthreads();
        const float mx = fmaxf(fmaxf(redm[0], redm[1]), fmaxf(redm[2], redm[3]));
        const float p = (t < NTOK) ? expf(sv - mx) : 0.f;
        float ls = p;
#pragma unroll
        for (int off = 32; off >= 1; off >>= 1) ls += __shfl_xor(ls, off);
        if (lane == 0) reds[w] = ls;
        __syncthreads();
        const float denom = (reds[0] + reds[1]) + (reds[2] + reds[3]);
        macc += p / denom;
        __syncthreads();                  // protect redm/reds for next h
    }

    if (t >= 1 && t < NTOK) {
        const float val = macc * (1.f / 12.f);
        vsh[t - 1] = val;
        outCls[(size_t)b * (NTOK - 1) + (t - 1)] = val;
    }
    __syncthreads();

    if (t < NTOK - 1) {
        const float vi = vsh[t];
        int rank = 0;
        for (int j = 0; j < NTOK - 1; j++) {
            const float vj = vsh[j];
            rank += (vj > vi) || (vj == vi && j < t);
        }
        if (rank < LEFT) {
            idxI[b * LEFT + rank]   = t;
            idxOut[b * LEFT + rank] = (float)t;
        }
    }
}

// index = broadcast idx over channel dim, float4-vectorized (CDIM%4==0)
__global__ void fill_index_kernel(const int* __restrict__ idxI,
                                  float* __restrict__ dst) {
    int tid = blockIdx.x * 256 + threadIdx.x;
    constexpr int C4 = CDIM / 4;
    if (tid >= BATCH * LEFT * C4) return;
    float v = (float)idxI[tid / C4];
    ((float4*)dst)[tid] = make_float4(v, v, v, v);
}

extern "C" void kernel_launch(void* const* d_in, const int* in_sizes, int n_in,
                              void* d_out, int out_size, void* d_ws, size_t ws_size,
                              hipStream_t stream) {
    const float* x      = (const float*)d_in[0];
    const float* qkv_w  = (const float*)d_in[1];  // [2304,768]
    const float* qkv_b  = (const float*)d_in[2];  // [2304]
    const float* proj_w = (const float*)d_in[3];  // [768,768]
    const float* proj_b = (const float*)d_in[4];  // [768]
    float* out = (float*)d_out;

    float*  ws    = (float*)d_ws;
    int*    idxi  = (int*)(ws + WS_IDXI);
    float*  qbW   = ws + WS_Q0;
    ushort* xb    = (ushort*)(ws + WS_XB);
    ushort* wb    = (ushort*)(ws + WS_WB);
    ushort* pb    = (ushort*)(ws + WS_PB);
    ushort* qb    = (ushort*)(ws + WS_QB);
    ushort* kb    = (ushort*)(ws + WS_KB);
    ushort* vd    = (ushort*)(ws + WS_VTB);  // dense v [MROWS][768] (fits region)
    ushort* aob   = (ushort*)(ws + WS_AOB);
    float*  U     = ws + WS_U;
    float*  S     = ws + WS_S;

    // 1) fused fp32 -> bf16 casts (x padded to MPAD, qkv_w, proj_w)
    cast_all_kernel<<<CAST_TOTAL / 256, 256, 0, stream>>>(x, qkv_w, proj_w, xb, wb, pb);

    // 2) Exact fp32 cls-score side path: fused q0-slice + qb + U, then scores
    u_kernel<<<BH, 256, 0, stream>>>(x, qkv_w, qkv_b, U, qbW);
    score_kernel<<<dim3((NTOK + 3) / 4, BATCH), 256, 0, stream>>>(x, U, S);

    // 3) QKV projection (128²/BK32 MFMA, 4 blocks/CU) + q/k split, v dense
    mfma_gemm128<1, 18><<<NROWT * 18, 256, 0, stream>>>(
        xb, wb, qkv_b, nullptr, qb, kb, vd, MROWS, 3 * CDIM);

    // 4) MFMA flash attention (block per bh; in-LDS V transpose) -> bf16 out
    attn_mfma_kernel<<<BH, 256, 0, stream>>>(qb, kb, vd, aob);

    // 5) Output projection (128²/BK32 MFMA) -> fp32 out
    mfma_gemm128<0, 6><<<NROWT * 6, 256, 0, stream>>>(
        aob, pb, proj_b, out + OUT_OFF_OUT, nullptr, nullptr, nullptr,
        MROWS, CDIM);

    // 6) Fused cls softmax + head-average + exact top-137 + cls output
    topk_fused_kernel<<<BATCH, 256, 0, stream>>>(S, qbW, idxi,
                                                 out + OUT_OFF_IDX,
                                                 out + OUT_OFF_CLS);

    // 7) Broadcast indices over channels (float4)
    fill_index_kernel<<<((size_t)BATCH * LEFT * (CDIM / 4) + 255) / 256, 256, 0, stream>>>(
        idxi, out + OUT_OFF_INDEX);
}